// Round 3
// baseline (6177.642 us; speedup 1.0000x reference)
//
#include <hip/hip_runtime.h>

typedef unsigned short u16;

#define BATCH  4
#define NSEQ   2048
#define DMODEL 512
#define TOK    8192   // BATCH*NSEQ

__device__ __forceinline__ float bf2f(u16 u) {
    unsigned int x = ((unsigned int)u) << 16;
    return __uint_as_float(x);
}
__device__ __forceinline__ u16 f2bf(float f) {
    unsigned int x = __float_as_uint(f);
    unsigned int r = (x + 0x7FFFu + ((x >> 16) & 1u)) >> 16;  // RNE
    return (u16)r;
}
// dual-dtype load: flag!=0 -> input tensors are fp32, else bf16
__device__ __forceinline__ float ldf(const void* p, size_t i, bool f32) {
    return f32 ? ((const float*)p)[i] : bf2f(((const u16*)p)[i]);
}
// dual-dtype store to d_out (IO dtypes are coupled: fp32 in => fp32 out)
__device__ __forceinline__ void stf(void* p, size_t i, float v, bool f32) {
    if (f32) ((float*)p)[i] = v;
    else     ((u16*)p)[i] = f2bf(v);
}

// ---------------------------------------------------------------------------
// Input dtype detection: for fp32 data, even-indexed u16s are float mantissa
// halves (uniform-random exponent-field bits); for bf16 data they are sane
// bf16 values (exponent near 127).
__global__ void detect_kernel(const u16* __restrict__ x, int* __restrict__ flag) {
    __shared__ int cnt;
    if (threadIdx.x == 0) cnt = 0;
    __syncthreads();
    int sane = 0;
    for (int i = threadIdx.x; i < 2048; i += blockDim.x) {
        u16 u = x[2 * i];
        int e = (u >> 7) & 0xFF;
        if (u == 0 || (e >= 100 && e <= 140)) sane++;
    }
    atomicAdd(&cnt, sane);
    __syncthreads();
    if (threadIdx.x == 0) *flag = (cnt >= 1024) ? 0 : 1;  // 1 => fp32 inputs
}

// ---------------------------------------------------------------------------
// Router: fp64 logits+softmax, then expert-preferred greedy assignment via
// bitonic sort per round (exact jax.lax.top_k tie semantics: prob desc, idx asc).
__global__ __launch_bounds__(1024) void router_kernel(
    const void* __restrict__ xg, const void* __restrict__ rw, const void* __restrict__ rb,
    const int* __restrict__ flag, int* __restrict__ dtok, float* __restrict__ rpw,
    void* __restrict__ outp)
{
    __shared__ float sprobs[NSEQ][4];     // 32 KB
    __shared__ unsigned int skey[NSEQ];   // 8 KB
    __shared__ int sassigned[NSEQ];       // 8 KB
    const int b = blockIdx.x;
    const int tid = threadIdx.x;
    const bool f32 = (*flag != 0);

    double rb0 = (double)ldf(rb, 0, f32), rb1 = (double)ldf(rb, 1, f32);
    double rb2 = (double)ldf(rb, 2, f32), rb3 = (double)ldf(rb, 3, f32);

    for (int n = tid; n < NSEQ; n += 1024) {
        double a0 = rb0, a1 = rb1, a2 = rb2, a3 = rb3;
        size_t xbase = ((size_t)b * NSEQ + n) * DMODEL;
        for (int d = 0; d < DMODEL; ++d) {
            double xv = (double)ldf(xg, xbase + d, f32);
            a0 += xv * (double)ldf(rw, (size_t)d * 4 + 0, f32);
            a1 += xv * (double)ldf(rw, (size_t)d * 4 + 1, f32);
            a2 += xv * (double)ldf(rw, (size_t)d * 4 + 2, f32);
            a3 += xv * (double)ldf(rw, (size_t)d * 4 + 3, f32);
        }
        double mx = fmax(fmax(a0, a1), fmax(a2, a3));
        double e0 = exp(a0 - mx), e1 = exp(a1 - mx), e2 = exp(a2 - mx), e3 = exp(a3 - mx);
        double s = e0 + e1 + e2 + e3;
        sprobs[n][0] = (float)(e0 / s);
        sprobs[n][1] = (float)(e1 / s);
        sprobs[n][2] = (float)(e2 / s);
        sprobs[n][3] = (float)(e3 / s);
        sassigned[n] = -1;
    }
    __syncthreads();

    for (int e = 3; e >= 0; --e) {
        int cap = (e == 0) ? 1024 : (e == 1) ? 512 : 256;
        for (int n = tid; n < NSEQ; n += 1024) skey[n] = (unsigned)n;
        // bitonic sort of token indices by (prob desc, idx asc); assigned -> prob=-1
        for (unsigned k = 2; k <= NSEQ; k <<= 1) {
            for (unsigned j = k >> 1; j > 0; j >>= 1) {
                __syncthreads();
                unsigned i = ((tid & ~(j - 1)) << 1) | (tid & (j - 1));
                unsigned ixj = i | j;
                unsigned a = skey[i], c = skey[ixj];
                float pa = (sassigned[a] < 0) ? sprobs[a][e] : -1.0f;
                float pc = (sassigned[c] < 0) ? sprobs[c][e] : -1.0f;
                bool after = (pa < pc) || (pa == pc && a > c);  // a should come after c
                bool up = ((i & k) == 0);
                if (after == up) { skey[i] = c; skey[ixj] = a; }
            }
        }
        __syncthreads();
        if (tid < cap) sassigned[skey[tid]] = e;
        __syncthreads();
    }

    const size_t base0 = (size_t)TOK * DMODEL;
    for (int n = tid; n < NSEQ; n += 1024) {
        int e = sassigned[n];
        size_t g = (size_t)b * NSEQ + n;
        dtok[g] = 64 << e;
        float rpv = sprobs[n][e];
        rpw[g] = rpv;
        stf(outp, base0 + g, (float)e, f32);        // assigned
        stf(outp, base0 + TOK + g, rpv, f32);       // rp
    }
}

// ---------------------------------------------------------------------------
// LayerNorm (+ nested mask). INMODE 0: input = native x (flag dtype);
// INMODE 1: input = fp32 ws (z). Output bf16, cols >= d_tok -> 0.
template <int INMODE>
__global__ __launch_bounds__(256) void ln_kernel(
    const void* __restrict__ in, const void* __restrict__ gw, const void* __restrict__ bw,
    const int* __restrict__ flag, const int* __restrict__ dtok, u16* __restrict__ out)
{
    const int row = blockIdx.x;
    const int tid = threadIdx.x;
    const bool f32 = (*flag != 0);
    size_t base = (size_t)row * DMODEL + tid * 2;
    float x0, x1;
    if (INMODE == 1 || f32) {
        float2 t = *(const float2*)((const float*)in + base);
        x0 = t.x; x1 = t.y;
    } else {
        const u16* p = (const u16*)in + base;
        x0 = bf2f(p[0]); x1 = bf2f(p[1]);
    }
    float s = x0 + x1;
    #pragma unroll
    for (int d2 = 32; d2 > 0; d2 >>= 1) s += __shfl_down(s, d2);
    __shared__ float red[4];
    if ((tid & 63) == 0) red[tid >> 6] = s;
    __syncthreads();
    s = red[0] + red[1] + red[2] + red[3];
    float mu = s * (1.0f / DMODEL);
    float d0 = x0 - mu, d1 = x1 - mu;
    float q2 = d0 * d0 + d1 * d1;
    #pragma unroll
    for (int d2 = 32; d2 > 0; d2 >>= 1) q2 += __shfl_down(q2, d2);
    __syncthreads();
    if ((tid & 63) == 0) red[tid >> 6] = q2;
    __syncthreads();
    q2 = red[0] + red[1] + red[2] + red[3];
    float inv = rsqrtf(q2 * (1.0f / DMODEL) + 1e-5f);
    int dt = dtok[row];
    int j0 = tid * 2;
    float r0 = (j0 < dt)     ? (d0 * inv * ldf(gw, j0, f32)     + ldf(bw, j0, f32))     : 0.0f;
    float r1 = (j0 + 1 < dt) ? (d1 * inv * ldf(gw, j0 + 1, f32) + ldf(bw, j0 + 1, f32)) : 0.0f;
    u16* op = out + (size_t)row * DMODEL + j0;
    op[0] = f2bf(r0); op[1] = f2bf(r1);
}

// ---------------------------------------------------------------------------
__device__ __forceinline__ float gelu_tanh(float x) {
    float x3 = x * x * x;
    float t = tanhf(0.7978845608028654f * (x + 0.044715f * x3));
    return 0.5f * x * (1.0f + t);
}

// Tiled SIMT GEMM: C[M,N] = A[M,K](bf16 ws) @ Bw[K,N](native dtype), 64x64 tile,
// 256 threads, 4x4 per thread, fp32 accumulate. Epilogues:
// MODE 0: qkv  -> mask (c mod 512) < d_tok, write bf16
// MODE 1: oproj-> +bias, mask, + x residual, write fp32 z
// MODE 2: w1   -> +bias, mask c < 4*d_tok, gelu, write bf16 hid
// MODE 3: w2   -> +bias, mask, out = z + (1+alpha*rp)*val, write d_out (IO dtype)
template <int MODE>
__global__ __launch_bounds__(256) void gemm_kernel(
    const u16* __restrict__ A, const void* __restrict__ Bw, const void* __restrict__ bias,
    const int* __restrict__ flag, const int* __restrict__ dtok, const float* __restrict__ rp,
    const void* __restrict__ resx, const float* __restrict__ resz, const void* __restrict__ alp,
    void* __restrict__ C, float* __restrict__ Cz, int Ncols, int Kdim)
{
    __shared__ __align__(16) float As[16][72];  // As[k][m]
    __shared__ __align__(16) float Bs[16][72];  // Bs[k][n]
    const int tid = threadIdx.x;
    const bool f32 = (*flag != 0);
    const int tx = tid & 15, ty = tid >> 4;
    const int m0 = blockIdx.x * 64, n0 = blockIdx.y * 64;
    float acc[4][4] = {};
    const int ar = tid >> 2, ak = (tid & 3) * 4;
    const int br = tid >> 4, bc = (tid & 15) * 4;
    for (int k0 = 0; k0 < Kdim; k0 += 16) {
        ushort4 av = *(const ushort4*)(A + (size_t)(m0 + ar) * Kdim + k0 + ak);
        float4 bv4;
        size_t bidx = (size_t)(k0 + br) * Ncols + n0 + bc;
        if (f32) {
            bv4 = *(const float4*)((const float*)Bw + bidx);
        } else {
            ushort4 u = *(const ushort4*)((const u16*)Bw + bidx);
            bv4 = make_float4(bf2f(u.x), bf2f(u.y), bf2f(u.z), bf2f(u.w));
        }
        As[ak + 0][ar] = bf2f(av.x);
        As[ak + 1][ar] = bf2f(av.y);
        As[ak + 2][ar] = bf2f(av.z);
        As[ak + 3][ar] = bf2f(av.w);
        *(float4*)&Bs[br][bc] = bv4;
        __syncthreads();
        #pragma unroll
        for (int kk = 0; kk < 16; ++kk) {
            const float4 a4 = *(const float4*)&As[kk][ty * 4];
            const float4 b4 = *(const float4*)&Bs[kk][tx * 4];
            float avr[4] = {a4.x, a4.y, a4.z, a4.w};
            float bvr[4] = {b4.x, b4.y, b4.z, b4.w};
            #pragma unroll
            for (int i = 0; i < 4; ++i)
                #pragma unroll
                for (int j = 0; j < 4; ++j)
                    acc[i][j] = fmaf(avr[i], bvr[j], acc[i][j]);
        }
        __syncthreads();
    }
    float alphav = 0.0f;
    if (MODE == 3) alphav = ldf(alp, 0, f32);
    #pragma unroll
    for (int i = 0; i < 4; ++i) {
        int r = m0 + ty * 4 + i;
        int dt = dtok[r];
        float gate = (MODE == 3) ? (1.0f + alphav * rp[r]) : 0.0f;
        #pragma unroll
        for (int j = 0; j < 4; ++j) {
            int c = n0 + tx * 4 + j;
            float v = acc[i][j];
            if (MODE == 0) {
                v = ((c & (DMODEL - 1)) < dt) ? v : 0.0f;
                ((u16*)C)[(size_t)r * Ncols + c] = f2bf(v);
            } else if (MODE == 1) {
                v += ldf(bias, c, f32);
                if (c >= dt) v = 0.0f;
                v += ldf(resx, (size_t)r * DMODEL + c, f32);
                Cz[(size_t)r * DMODEL + c] = v;
            } else if (MODE == 2) {
                v += ldf(bias, c, f32);
                v = (c < 4 * dt) ? gelu_tanh(v) : 0.0f;
                ((u16*)C)[(size_t)r * Ncols + c] = f2bf(v);
            } else {
                v += ldf(bias, c, f32);
                if (c >= dt) v = 0.0f;
                float outv = resz[(size_t)r * DMODEL + c] + gate * v;
                stf(C, (size_t)r * DMODEL + c, outv, f32);
            }
        }
    }
}

// ---------------------------------------------------------------------------
// Straightforward flash attention, exactly mirroring the reference:
// ALL 2048 queries x ALL 2048 keys per (batch, head). Masked tokens' k and v
// are already exactly zero in the qkv buffer, so ineligible keys contribute
// exp(0) to the denominator and 0 to the numerator automatically.
// Query-side output mask (o*m) applied in the epilogue from dtok.
// Block = 64 queries x 4 key-chunks (thread=(ql,ck)); quad-shuffle merge.
__global__ __launch_bounds__(256) void attn_kernel(
    const u16* __restrict__ qkv, const int* __restrict__ dtok, u16* __restrict__ o)
{
    const int blk = blockIdx.x;
    const int qc = blk & 31;
    const int h  = (blk >> 5) & 7;
    const int b  = blk >> 8;
    const int tid = threadIdx.x;
    const int ql = tid >> 2, ck = tid & 3;
    const int q_tok = qc * 64 + ql;
    const size_t row = (size_t)b * NSEQ + q_tok;
    const u16* qbase = qkv + row * 1536 + h * 64;
    float q[64];
    #pragma unroll
    for (int d4 = 0; d4 < 16; ++d4) {
        ushort4 u = *(const ushort4*)(qbase + d4 * 4);
        q[d4 * 4 + 0] = bf2f(u.x); q[d4 * 4 + 1] = bf2f(u.y);
        q[d4 * 4 + 2] = bf2f(u.z); q[d4 * 4 + 3] = bf2f(u.w);
    }
    float acc[64];
    #pragma unroll
    for (int d = 0; d < 64; ++d) acc[d] = 0.0f;
    float m = -INFINITY, l = 0.0f;
    for (int kt = ck * 512; kt < ck * 512 + 512; ++kt) {
        const u16* kb = qkv + ((size_t)b * NSEQ + kt) * 1536 + 512 + h * 64;
        float s = 0.0f;
        #pragma unroll
        for (int d4 = 0; d4 < 16; ++d4) {
            ushort4 u = *(const ushort4*)(kb + d4 * 4);
            s = fmaf(q[d4 * 4 + 0], bf2f(u.x), s);
            s = fmaf(q[d4 * 4 + 1], bf2f(u.y), s);
            s = fmaf(q[d4 * 4 + 2], bf2f(u.z), s);
            s = fmaf(q[d4 * 4 + 3], bf2f(u.w), s);
        }
        s *= 0.125f;  // 1/sqrt(64)
        if (s > m) {
            float sc = __expf(m - s);
            l *= sc;
            #pragma unroll
            for (int d = 0; d < 64; ++d) acc[d] *= sc;
            m = s;
        }
        float p = __expf(s - m);
        l += p;
        const u16* vb = kb + 512;
        #pragma unroll
        for (int d4 = 0; d4 < 16; ++d4) {
            ushort4 u = *(const ushort4*)(vb + d4 * 4);
            acc[d4 * 4 + 0] = fmaf(p, bf2f(u.x), acc[d4 * 4 + 0]);
            acc[d4 * 4 + 1] = fmaf(p, bf2f(u.y), acc[d4 * 4 + 1]);
            acc[d4 * 4 + 2] = fmaf(p, bf2f(u.z), acc[d4 * 4 + 2]);
            acc[d4 * 4 + 3] = fmaf(p, bf2f(u.w), acc[d4 * 4 + 3]);
        }
    }
    // merge 4 key-chunks across the quad of lanes
    float mo = m;
    mo = fmaxf(mo, __shfl_xor(mo, 1));
    mo = fmaxf(mo, __shfl_xor(mo, 2));
    float ec = __expf(m - mo);
    float lp = l * ec;
    lp += __shfl_xor(lp, 1);
    lp += __shfl_xor(lp, 2);
    float rinv = 1.0f / lp;
    const bool elig = dtok[row] > h * 64;  // query-side o*m mask (head-aligned)
    u16* ob = o + row * DMODEL + h * 64 + ck * 16;
    #pragma unroll
    for (int d = 0; d < 64; ++d) {
        float t = acc[d] * ec;
        t += __shfl_xor(t, 1);
        t += __shfl_xor(t, 2);
        if ((d >> 4) == ck) ob[d & 15] = f2bf(elig ? t * rinv : 0.0f);
    }
}

// ---------------------------------------------------------------------------
extern "C" void kernel_launch(void* const* d_in, const int* in_sizes, int n_in,
                              void* d_out, int out_size, void* d_ws, size_t ws_size,
                              hipStream_t stream)
{
    (void)in_sizes; (void)n_in; (void)out_size; (void)ws_size;
    const void* x    = d_in[0];
    const void* r_w  = d_in[1];
    const void* r_b  = d_in[2];
    const void* g1   = d_in[3];
    const void* b1   = d_in[4];
    const void* g2   = d_in[5];
    const void* b2   = d_in[6];
    const void* wqkv = d_in[7];
    const void* wo   = d_in[8];
    const void* bo   = d_in[9];
    const void* w1   = d_in[10];
    const void* b1f  = d_in[11];
    const void* w2   = d_in[12];
    const void* b2f  = d_in[13];
    const void* alp  = d_in[14];

    // Workspace overlay (56.07 MB total):
    //   A [0,8M):        h (bf16), later hm (bf16)
    //   B [8M,56M):      qkv 24M (bf16); z = fp32 @ [8M,24M); ob @ [32M,40M);
    //                    hid 32M @ [24M,56M) (clobbers dead qkv-tail and ob)
    //   meta @ [56M, +66K)
    const size_t MB = 1024 * 1024;
    char* ws = (char*)d_ws;
    u16*   h    = (u16*)  (ws);                 // [0, 8M)
    u16*   hm   = (u16*)  (ws);
    u16*   qkv  = (u16*)  (ws + 8 * MB);        // [8M, 32M)
    float* z    = (float*)(ws + 8 * MB);        // [8M, 24M)
    u16*   ob   = (u16*)  (ws + 32 * MB);       // [32M, 40M)
    u16*   hid  = (u16*)  (ws + 24 * MB);       // [24M, 56M)
    int*   flag = (int*)  (ws + 56 * MB);
    int*   dtok = (int*)  (ws + 56 * MB + 256);
    float* rpw  = (float*)(ws + 56 * MB + 256 + 32768);

    detect_kernel<<<1, 256, 0, stream>>>((const u16*)x, flag);
    router_kernel<<<BATCH, 1024, 0, stream>>>(x, r_w, r_b, flag, dtok, rpw, d_out);
    ln_kernel<0><<<TOK, 256, 0, stream>>>(x, g1, b1, flag, dtok, h);
    gemm_kernel<0><<<dim3(TOK / 64, 1536 / 64), 256, 0, stream>>>(
        h, wqkv, nullptr, flag, dtok, nullptr, nullptr, nullptr, nullptr,
        qkv, nullptr, 1536, 512);
    attn_kernel<<<BATCH * 8 * (NSEQ / 64), 256, 0, stream>>>(qkv, dtok, ob);
    gemm_kernel<1><<<dim3(TOK / 64, 512 / 64), 256, 0, stream>>>(
        ob, wo, bo, flag, dtok, nullptr, x, nullptr, nullptr,
        nullptr, z, 512, 512);
    ln_kernel<1><<<TOK, 256, 0, stream>>>(z, g2, b2, flag, dtok, hm);
    gemm_kernel<2><<<dim3(TOK / 64, 2048 / 64), 256, 0, stream>>>(
        hm, w1, b1f, flag, dtok, nullptr, nullptr, nullptr, nullptr,
        hid, nullptr, 2048, 512);
    gemm_kernel<3><<<dim3(TOK / 64, 512 / 64), 256, 0, stream>>>(
        hid, w2, b2f, flag, dtok, rpw, nullptr, z, alp,
        d_out, nullptr, 512, 2048);
}

// Round 4
// 1416.065 us; speedup vs baseline: 4.3625x; 4.3625x over previous
//
#include <hip/hip_runtime.h>

typedef unsigned short u16;

#define BATCH  4
#define NSEQ   2048
#define DMODEL 512
#define TOK    8192   // BATCH*NSEQ

__device__ __forceinline__ float bf2f(u16 u) {
    unsigned int x = ((unsigned int)u) << 16;
    return __uint_as_float(x);
}
__device__ __forceinline__ u16 f2bf(float f) {
    unsigned int x = __float_as_uint(f);
    unsigned int r = (x + 0x7FFFu + ((x >> 16) & 1u)) >> 16;  // RNE
    return (u16)r;
}
// dual-dtype load: flag!=0 -> input tensors are fp32, else bf16
__device__ __forceinline__ float ldf(const void* p, size_t i, bool f32) {
    return f32 ? ((const float*)p)[i] : bf2f(((const u16*)p)[i]);
}
// dual-dtype store to d_out (IO dtypes are coupled: fp32 in => fp32 out)
__device__ __forceinline__ void stf(void* p, size_t i, float v, bool f32) {
    if (f32) ((float*)p)[i] = v;
    else     ((u16*)p)[i] = f2bf(v);
}

// ---------------------------------------------------------------------------
// Input dtype detection (kept for robustness; fp32 confirmed by round 3).
__global__ void detect_kernel(const u16* __restrict__ x, int* __restrict__ flag) {
    __shared__ int cnt;
    if (threadIdx.x == 0) cnt = 0;
    __syncthreads();
    int sane = 0;
    for (int i = threadIdx.x; i < 2048; i += blockDim.x) {
        u16 u = x[2 * i];
        int e = (u >> 7) & 0xFF;
        if (u == 0 || (e >= 100 && e <= 140)) sane++;
    }
    atomicAdd(&cnt, sane);
    __syncthreads();
    if (threadIdx.x == 0) *flag = (cnt >= 1024) ? 0 : 1;  // 1 => fp32 inputs
}

// ---------------------------------------------------------------------------
// Router: fp64 logits+softmax, then expert-preferred greedy assignment via
// bitonic sort per round (exact jax.lax.top_k tie semantics: prob desc, idx asc).
__global__ __launch_bounds__(1024) void router_kernel(
    const void* __restrict__ xg, const void* __restrict__ rw, const void* __restrict__ rb,
    const int* __restrict__ flag, int* __restrict__ dtok, float* __restrict__ rpw,
    void* __restrict__ outp)
{
    __shared__ float sprobs[NSEQ][4];     // 32 KB
    __shared__ unsigned int skey[NSEQ];   // 8 KB
    __shared__ int sassigned[NSEQ];       // 8 KB
    const int b = blockIdx.x;
    const int tid = threadIdx.x;
    const bool f32 = (*flag != 0);

    double rb0 = (double)ldf(rb, 0, f32), rb1 = (double)ldf(rb, 1, f32);
    double rb2 = (double)ldf(rb, 2, f32), rb3 = (double)ldf(rb, 3, f32);

    for (int n = tid; n < NSEQ; n += 1024) {
        double a0 = rb0, a1 = rb1, a2 = rb2, a3 = rb3;
        size_t xbase = ((size_t)b * NSEQ + n) * DMODEL;
        for (int d = 0; d < DMODEL; ++d) {
            double xv = (double)ldf(xg, xbase + d, f32);
            a0 += xv * (double)ldf(rw, (size_t)d * 4 + 0, f32);
            a1 += xv * (double)ldf(rw, (size_t)d * 4 + 1, f32);
            a2 += xv * (double)ldf(rw, (size_t)d * 4 + 2, f32);
            a3 += xv * (double)ldf(rw, (size_t)d * 4 + 3, f32);
        }
        double mx = fmax(fmax(a0, a1), fmax(a2, a3));
        double e0 = exp(a0 - mx), e1 = exp(a1 - mx), e2 = exp(a2 - mx), e3 = exp(a3 - mx);
        double s = e0 + e1 + e2 + e3;
        sprobs[n][0] = (float)(e0 / s);
        sprobs[n][1] = (float)(e1 / s);
        sprobs[n][2] = (float)(e2 / s);
        sprobs[n][3] = (float)(e3 / s);
        sassigned[n] = -1;
    }
    __syncthreads();

    for (int e = 3; e >= 0; --e) {
        int cap = (e == 0) ? 1024 : (e == 1) ? 512 : 256;
        for (int n = tid; n < NSEQ; n += 1024) skey[n] = (unsigned)n;
        // bitonic sort of token indices by (prob desc, idx asc); assigned -> prob=-1
        for (unsigned k = 2; k <= NSEQ; k <<= 1) {
            for (unsigned j = k >> 1; j > 0; j >>= 1) {
                __syncthreads();
                unsigned i = ((tid & ~(j - 1)) << 1) | (tid & (j - 1));
                unsigned ixj = i | j;
                unsigned a = skey[i], c = skey[ixj];
                float pa = (sassigned[a] < 0) ? sprobs[a][e] : -1.0f;
                float pc = (sassigned[c] < 0) ? sprobs[c][e] : -1.0f;
                bool after = (pa < pc) || (pa == pc && a > c);  // a should come after c
                bool up = ((i & k) == 0);
                if (after == up) { skey[i] = c; skey[ixj] = a; }
            }
        }
        __syncthreads();
        if (tid < cap) sassigned[skey[tid]] = e;
        __syncthreads();
    }

    const size_t base0 = (size_t)TOK * DMODEL;
    for (int n = tid; n < NSEQ; n += 1024) {
        int e = sassigned[n];
        size_t g = (size_t)b * NSEQ + n;
        dtok[g] = 64 << e;
        float rpv = sprobs[n][e];
        rpw[g] = rpv;
        stf(outp, base0 + g, (float)e, f32);        // assigned
        stf(outp, base0 + TOK + g, rpv, f32);       // rp
    }
}

// ---------------------------------------------------------------------------
// LayerNorm (+ nested mask). INMODE 0: input = native x (flag dtype);
// INMODE 1: input = fp32 ws (z). Output bf16, cols >= d_tok -> 0.
template <int INMODE>
__global__ __launch_bounds__(256) void ln_kernel(
    const void* __restrict__ in, const void* __restrict__ gw, const void* __restrict__ bw,
    const int* __restrict__ flag, const int* __restrict__ dtok, u16* __restrict__ out)
{
    const int row = blockIdx.x;
    const int tid = threadIdx.x;
    const bool f32 = (*flag != 0);
    size_t base = (size_t)row * DMODEL + tid * 2;
    float x0, x1;
    if (INMODE == 1 || f32) {
        float2 t = *(const float2*)((const float*)in + base);
        x0 = t.x; x1 = t.y;
    } else {
        const u16* p = (const u16*)in + base;
        x0 = bf2f(p[0]); x1 = bf2f(p[1]);
    }
    float s = x0 + x1;
    #pragma unroll
    for (int d2 = 32; d2 > 0; d2 >>= 1) s += __shfl_down(s, d2);
    __shared__ float red[4];
    if ((tid & 63) == 0) red[tid >> 6] = s;
    __syncthreads();
    s = red[0] + red[1] + red[2] + red[3];
    float mu = s * (1.0f / DMODEL);
    float d0 = x0 - mu, d1 = x1 - mu;
    float q2 = d0 * d0 + d1 * d1;
    #pragma unroll
    for (int d2 = 32; d2 > 0; d2 >>= 1) q2 += __shfl_down(q2, d2);
    __syncthreads();
    if ((tid & 63) == 0) red[tid >> 6] = q2;
    __syncthreads();
    q2 = red[0] + red[1] + red[2] + red[3];
    float inv = rsqrtf(q2 * (1.0f / DMODEL) + 1e-5f);
    int dt = dtok[row];
    int j0 = tid * 2;
    float r0 = (j0 < dt)     ? (d0 * inv * ldf(gw, j0, f32)     + ldf(bw, j0, f32))     : 0.0f;
    float r1 = (j0 + 1 < dt) ? (d1 * inv * ldf(gw, j0 + 1, f32) + ldf(bw, j0 + 1, f32)) : 0.0f;
    u16* op = out + (size_t)row * DMODEL + j0;
    op[0] = f2bf(r0); op[1] = f2bf(r1);
}

// ---------------------------------------------------------------------------
__device__ __forceinline__ float gelu_tanh(float x) {
    float x3 = x * x * x;
    float t = tanhf(0.7978845608028654f * (x + 0.044715f * x3));
    return 0.5f * x * (1.0f + t);
}

// Tiled SIMT GEMM: C[M,N] = A[M,K](bf16 ws) @ Bw[K,N](native dtype), 64x64 tile,
// 256 threads, 4x4 per thread, fp32 accumulate. Epilogues:
// MODE 0: qkv  -> mask (c mod 512) < d_tok, write bf16
// MODE 1: oproj-> +bias, mask, + x residual, write fp32 z
// MODE 2: w1   -> +bias, mask c < 4*d_tok, gelu, write bf16 hid
// MODE 3: w2   -> +bias, mask, out = z + (1+alpha*rp)*val, write d_out (IO dtype)
template <int MODE>
__global__ __launch_bounds__(256) void gemm_kernel(
    const u16* __restrict__ A, const void* __restrict__ Bw, const void* __restrict__ bias,
    const int* __restrict__ flag, const int* __restrict__ dtok, const float* __restrict__ rp,
    const void* __restrict__ resx, const float* __restrict__ resz, const void* __restrict__ alp,
    void* __restrict__ C, float* __restrict__ Cz, int Ncols, int Kdim)
{
    __shared__ __align__(16) float As[16][72];  // As[k][m]
    __shared__ __align__(16) float Bs[16][72];  // Bs[k][n]
    const int tid = threadIdx.x;
    const bool f32 = (*flag != 0);
    const int tx = tid & 15, ty = tid >> 4;
    const int m0 = blockIdx.x * 64, n0 = blockIdx.y * 64;
    float acc[4][4] = {};
    const int ar = tid >> 2, ak = (tid & 3) * 4;
    const int br = tid >> 4, bc = (tid & 15) * 4;
    for (int k0 = 0; k0 < Kdim; k0 += 16) {
        ushort4 av = *(const ushort4*)(A + (size_t)(m0 + ar) * Kdim + k0 + ak);
        float4 bv4;
        size_t bidx = (size_t)(k0 + br) * Ncols + n0 + bc;
        if (f32) {
            bv4 = *(const float4*)((const float*)Bw + bidx);
        } else {
            ushort4 u = *(const ushort4*)((const u16*)Bw + bidx);
            bv4 = make_float4(bf2f(u.x), bf2f(u.y), bf2f(u.z), bf2f(u.w));
        }
        As[ak + 0][ar] = bf2f(av.x);
        As[ak + 1][ar] = bf2f(av.y);
        As[ak + 2][ar] = bf2f(av.z);
        As[ak + 3][ar] = bf2f(av.w);
        *(float4*)&Bs[br][bc] = bv4;
        __syncthreads();
        #pragma unroll
        for (int kk = 0; kk < 16; ++kk) {
            const float4 a4 = *(const float4*)&As[kk][ty * 4];
            const float4 b4 = *(const float4*)&Bs[kk][tx * 4];
            float avr[4] = {a4.x, a4.y, a4.z, a4.w};
            float bvr[4] = {b4.x, b4.y, b4.z, b4.w};
            #pragma unroll
            for (int i = 0; i < 4; ++i)
                #pragma unroll
                for (int j = 0; j < 4; ++j)
                    acc[i][j] = fmaf(avr[i], bvr[j], acc[i][j]);
        }
        __syncthreads();
    }
    float alphav = 0.0f;
    if (MODE == 3) alphav = ldf(alp, 0, f32);
    #pragma unroll
    for (int i = 0; i < 4; ++i) {
        int r = m0 + ty * 4 + i;
        int dt = dtok[r];
        float gate = (MODE == 3) ? (1.0f + alphav * rp[r]) : 0.0f;
        #pragma unroll
        for (int j = 0; j < 4; ++j) {
            int c = n0 + tx * 4 + j;
            float v = acc[i][j];
            if (MODE == 0) {
                v = ((c & (DMODEL - 1)) < dt) ? v : 0.0f;
                ((u16*)C)[(size_t)r * Ncols + c] = f2bf(v);
            } else if (MODE == 1) {
                v += ldf(bias, c, f32);
                if (c >= dt) v = 0.0f;
                v += ldf(resx, (size_t)r * DMODEL + c, f32);
                Cz[(size_t)r * DMODEL + c] = v;
            } else if (MODE == 2) {
                v += ldf(bias, c, f32);
                v = (c < 4 * dt) ? gelu_tanh(v) : 0.0f;
                ((u16*)C)[(size_t)r * Ncols + c] = f2bf(v);
            } else {
                v += ldf(bias, c, f32);
                if (c >= dt) v = 0.0f;
                float outv = resz[(size_t)r * DMODEL + c] + gate * v;
                stf(C, (size_t)r * DMODEL + c, outv, f32);
            }
        }
    }
}

// ---------------------------------------------------------------------------
// MFMA flash attention (16x16x32 bf16). Per block: (b, h, 64 queries), 4 waves,
// each wave owns 16 query rows. Loop over 32 KV tiles of 64 keys.
// Layout assumptions (k-permutation within a lane's 8 elements cancels because
// BOTH operands of each MFMA use the same assumed k-order):
//   A-frag: lane holds A[m=lane%16][k=8*(lane/16)+j]
//   B-frag: lane holds B[k=8*(lane/16)+j][n=lane%16]
//   D:      lane holds D[m=4*(lane/16)+r][n=lane%16]   (HW-verified mapping)
// Masked tokens' K/V are exactly zero -> full softmax over all 2048 keys is
// faithful; ineligible queries masked at the output write.
__global__ __launch_bounds__(256) void attn_kernel(
    const u16* __restrict__ qkv, const int* __restrict__ dtok, u16* __restrict__ o)
{
    typedef __attribute__((ext_vector_type(8))) __bf16 bf16x8;
    typedef __attribute__((ext_vector_type(4))) float f32x4;
    __shared__ u16 Ks[64 * 72];       // K tile, row stride 72 (144 B, 16B-aligned)
    __shared__ u16 Vs[64 * 76];       // V tile row-major, stride 76 (152 B)
    __shared__ u16 Ps[4 * 16 * 72];   // per-wave P tile [16][72]

    const int bid = blockIdx.x;
    const int qblk = bid & 31, hh = (bid >> 5) & 7, b = bid >> 8;
    const int tid = threadIdx.x;
    const int w = tid >> 6, l = tid & 63;
    const int ln = l & 15, lg = l >> 4;

    const size_t bbase = (size_t)b * NSEQ;
    const int q0 = qblk * 64 + w * 16;

    // Q fragments, pre-scaled by 1/8 (exact in bf16)
    bf16x8 qa[2];
    {
        const u16* qrow = qkv + (bbase + q0 + ln) * 1536 + hh * 64;
        #pragma unroll
        for (int s = 0; s < 2; ++s) {
            bf16x8 t = *reinterpret_cast<const bf16x8*>(qrow + 8 * lg + 32 * s);
            #pragma unroll
            for (int j = 0; j < 8; ++j) t[j] = (__bf16)((float)t[j] * 0.125f);
            qa[s] = t;
        }
    }

    f32x4 oacc[4];
    #pragma unroll
    for (int d0 = 0; d0 < 4; ++d0) oacc[d0] = f32x4{0.f, 0.f, 0.f, 0.f};
    float mold[4] = {-INFINITY, -INFINITY, -INFINITY, -INFINITY};
    float lsum[4] = {0.f, 0.f, 0.f, 0.f};
    u16* Pw = Ps + w * 16 * 72;

    for (int t0 = 0; t0 < NSEQ; t0 += 64) {
        __syncthreads();  // previous tile's compute done before LDS overwrite
        #pragma unroll
        for (int p = 0; p < 2; ++p) {
            int idx = p * 256 + tid;
            int row = idx >> 3, c8 = (idx & 7) * 8;
            const u16* src = qkv + (bbase + t0 + row) * 1536 + 512 + hh * 64 + c8;
            uint4 kv = *reinterpret_cast<const uint4*>(src);
            *reinterpret_cast<uint4*>(&Ks[row * 72 + c8]) = kv;
            uint4 vv = *reinterpret_cast<const uint4*>(src + 512);
            *reinterpret_cast<uint2*>(&Vs[row * 76 + c8]) = make_uint2(vv.x, vv.y);
            *reinterpret_cast<uint2*>(&Vs[row * 76 + c8 + 4]) = make_uint2(vv.z, vv.w);
        }
        __syncthreads();

        // S[16 q x 64 k] = Q.K^T (Q pre-scaled)
        f32x4 sa[4];
        #pragma unroll
        for (int kb = 0; kb < 4; ++kb) sa[kb] = f32x4{0.f, 0.f, 0.f, 0.f};
        #pragma unroll
        for (int kb = 0; kb < 4; ++kb) {
            #pragma unroll
            for (int s = 0; s < 2; ++s) {
                bf16x8 kf = *reinterpret_cast<const bf16x8*>(
                    &Ks[(kb * 16 + ln) * 72 + 8 * lg + 32 * s]);
                sa[kb] = __builtin_amdgcn_mfma_f32_16x16x32_bf16(qa[s], kf, sa[kb], 0, 0, 0);
            }
        }

        // online softmax; rows m = 4*lg + r live in the 16-lane group
        float nm[4], sc[4];
        #pragma unroll
        for (int r = 0; r < 4; ++r) {
            float mx = fmaxf(fmaxf(sa[0][r], sa[1][r]), fmaxf(sa[2][r], sa[3][r]));
            mx = fmaxf(mx, __shfl_xor(mx, 1));
            mx = fmaxf(mx, __shfl_xor(mx, 2));
            mx = fmaxf(mx, __shfl_xor(mx, 4));
            mx = fmaxf(mx, __shfl_xor(mx, 8));
            nm[r] = fmaxf(mold[r], mx);
            sc[r] = __expf(mold[r] - nm[r]);
            mold[r] = nm[r];
        }
        float psum[4] = {0.f, 0.f, 0.f, 0.f};
        #pragma unroll
        for (int kb = 0; kb < 4; ++kb) {
            #pragma unroll
            for (int r = 0; r < 4; ++r) {
                float p = __expf(sa[kb][r] - nm[r]);
                psum[r] += p;
                Pw[(4 * lg + r) * 72 + kb * 16 + ln] = f2bf(p);
            }
        }
        #pragma unroll
        for (int r = 0; r < 4; ++r) {
            float s = psum[r];
            s += __shfl_xor(s, 1);
            s += __shfl_xor(s, 2);
            s += __shfl_xor(s, 4);
            s += __shfl_xor(s, 8);
            lsum[r] = lsum[r] * sc[r] + s;
            #pragma unroll
            for (int d0 = 0; d0 < 4; ++d0) oacc[d0][r] *= sc[r];
        }
        asm volatile("s_waitcnt lgkmcnt(0)" ::: "memory");  // P writes visible

        // O += P.V
        #pragma unroll
        for (int d0 = 0; d0 < 4; ++d0) {
            #pragma unroll
            for (int s = 0; s < 2; ++s) {
                bf16x8 pf = *reinterpret_cast<const bf16x8*>(
                    &Pw[ln * 72 + 8 * lg + 32 * s]);
                bf16x8 vf;
                #pragma unroll
                for (int j = 0; j < 8; ++j) {
                    union { u16 u; __bf16 y; } cv;
                    cv.u = Vs[(8 * lg + 32 * s + j) * 76 + d0 * 16 + ln];
                    vf[j] = cv.y;
                }
                oacc[d0] = __builtin_amdgcn_mfma_f32_16x16x32_bf16(pf, vf, oacc[d0], 0, 0, 0);
            }
        }
    }

    #pragma unroll
    for (int r = 0; r < 4; ++r) {
        int qrow = q0 + 4 * lg + r;
        bool elig = dtok[bbase + qrow] > hh * 64;  // query-side o*m mask
        float rinv = elig ? (1.0f / lsum[r]) : 0.0f;
        u16* obp = o + (bbase + qrow) * DMODEL + hh * 64;
        #pragma unroll
        for (int d0 = 0; d0 < 4; ++d0)
            obp[d0 * 16 + ln] = f2bf(oacc[d0][r] * rinv);
    }
}

// ---------------------------------------------------------------------------
extern "C" void kernel_launch(void* const* d_in, const int* in_sizes, int n_in,
                              void* d_out, int out_size, void* d_ws, size_t ws_size,
                              hipStream_t stream)
{
    (void)in_sizes; (void)n_in; (void)out_size; (void)ws_size;
    const void* x    = d_in[0];
    const void* r_w  = d_in[1];
    const void* r_b  = d_in[2];
    const void* g1   = d_in[3];
    const void* b1   = d_in[4];
    const void* g2   = d_in[5];
    const void* b2   = d_in[6];
    const void* wqkv = d_in[7];
    const void* wo   = d_in[8];
    const void* bo   = d_in[9];
    const void* w1   = d_in[10];
    const void* b1f  = d_in[11];
    const void* w2   = d_in[12];
    const void* b2f  = d_in[13];
    const void* alp  = d_in[14];

    // Workspace overlay (56.07 MB total):
    //   A [0,8M):        h (bf16), later hm (bf16)
    //   B [8M,56M):      qkv 24M (bf16); z = fp32 @ [8M,24M); ob @ [32M,40M);
    //                    hid 32M @ [24M,56M) (clobbers dead qkv-tail and ob)
    //   meta @ [56M, +66K)
    const size_t MB = 1024 * 1024;
    char* ws = (char*)d_ws;
    u16*   h    = (u16*)  (ws);                 // [0, 8M)
    u16*   hm   = (u16*)  (ws);
    u16*   qkv  = (u16*)  (ws + 8 * MB);        // [8M, 32M)
    float* z    = (float*)(ws + 8 * MB);        // [8M, 24M)
    u16*   ob   = (u16*)  (ws + 32 * MB);       // [32M, 40M)
    u16*   hid  = (u16*)  (ws + 24 * MB);       // [24M, 56M)
    int*   flag = (int*)  (ws + 56 * MB);
    int*   dtok = (int*)  (ws + 56 * MB + 256);
    float* rpw  = (float*)(ws + 56 * MB + 256 + 32768);

    detect_kernel<<<1, 256, 0, stream>>>((const u16*)x, flag);
    router_kernel<<<BATCH, 1024, 0, stream>>>(x, r_w, r_b, flag, dtok, rpw, d_out);
    ln_kernel<0><<<TOK, 256, 0, stream>>>(x, g1, b1, flag, dtok, h);
    gemm_kernel<0><<<dim3(TOK / 64, 1536 / 64), 256, 0, stream>>>(
        h, wqkv, nullptr, flag, dtok, nullptr, nullptr, nullptr, nullptr,
        qkv, nullptr, 1536, 512);
    attn_kernel<<<BATCH * 8 * (NSEQ / 64), 256, 0, stream>>>(qkv, dtok, ob);
    gemm_kernel<1><<<dim3(TOK / 64, 512 / 64), 256, 0, stream>>>(
        ob, wo, bo, flag, dtok, nullptr, x, nullptr, nullptr,
        nullptr, z, 512, 512);
    ln_kernel<1><<<TOK, 256, 0, stream>>>(z, g2, b2, flag, dtok, hm);
    gemm_kernel<2><<<dim3(TOK / 64, 2048 / 64), 256, 0, stream>>>(
        hm, w1, b1f, flag, dtok, nullptr, nullptr, nullptr, nullptr,
        hid, nullptr, 2048, 512);
    gemm_kernel<3><<<dim3(TOK / 64, 512 / 64), 256, 0, stream>>>(
        hid, w2, b2f, flag, dtok, rpw, nullptr, z, alp,
        d_out, nullptr, 512, 2048);
}

// Round 5
// 359.248 us; speedup vs baseline: 17.1961x; 3.9418x over previous
//
#include <hip/hip_runtime.h>

typedef unsigned short u16;
typedef unsigned long long u64;

#define BATCH  4
#define NSEQ   2048
#define DMODEL 512
#define TOK    8192   // BATCH*NSEQ

typedef __attribute__((ext_vector_type(8))) __bf16 bf16x8;
typedef __attribute__((ext_vector_type(4))) float f32x4;

__device__ __forceinline__ float bf2f(u16 u) {
    unsigned int x = ((unsigned int)u) << 16;
    return __uint_as_float(x);
}
__device__ __forceinline__ u16 f2bf(float f) {
    unsigned int x = __float_as_uint(f);
    unsigned int r = (x + 0x7FFFu + ((x >> 16) & 1u)) >> 16;  // RNE
    return (u16)r;
}
// dual-dtype load: flag!=0 -> input tensors are fp32, else bf16
__device__ __forceinline__ float ldf(const void* p, size_t i, bool f32) {
    return f32 ? ((const float*)p)[i] : bf2f(((const u16*)p)[i]);
}
// dual-dtype store to d_out (IO dtypes are coupled: fp32 in => fp32 out)
__device__ __forceinline__ void stf(void* p, size_t i, float v, bool f32) {
    if (f32) ((float*)p)[i] = v;
    else     ((u16*)p)[i] = f2bf(v);
}

// ---------------------------------------------------------------------------
// Input dtype detection (fp32 confirmed by round 3; kept for robustness).
__global__ void detect_kernel(const u16* __restrict__ x, int* __restrict__ flag) {
    __shared__ int cnt;
    if (threadIdx.x == 0) cnt = 0;
    __syncthreads();
    int sane = 0;
    for (int i = threadIdx.x; i < 2048; i += blockDim.x) {
        u16 u = x[2 * i];
        int e = (u >> 7) & 0xFF;
        if (u == 0 || (e >= 100 && e <= 140)) sane++;
    }
    atomicAdd(&cnt, sane);
    __syncthreads();
    if (threadIdx.x == 0) *flag = (cnt >= 1024) ? 0 : 1;  // 1 => fp32 inputs
}

// ---------------------------------------------------------------------------
// Weight convert + transpose: in (native) [K][N] -> out bf16 [N][K].
__global__ __launch_bounds__(256) void wconv_kernel(
    const void* __restrict__ in, const int* __restrict__ flag,
    u16* __restrict__ out, int K, int N)
{
    __shared__ float t[32][33];
    const bool f32 = (*flag != 0);
    const int kb = blockIdx.x * 32, nb = blockIdx.y * 32;
    const int tx = threadIdx.x & 7, ty = threadIdx.x >> 3;
    #pragma unroll
    for (int i = 0; i < 4; ++i)
        t[ty][tx * 4 + i] = ldf(in, (size_t)(kb + ty) * N + nb + tx * 4 + i, f32);
    __syncthreads();
    #pragma unroll
    for (int i = 0; i < 4; ++i)
        out[(size_t)(nb + ty) * K + kb + tx * 4 + i] = f2bf(t[tx * 4 + i][ty]);
}

// ---------------------------------------------------------------------------
// Router phase A: fp64 logits + softmax, one wave per token.
__global__ __launch_bounds__(256) void rprob_kernel(
    const void* __restrict__ xg, const void* __restrict__ rw, const void* __restrict__ rb,
    const int* __restrict__ flag, float* __restrict__ probs)
{
    __shared__ float srw[DMODEL * 4];
    const bool f32 = (*flag != 0);
    for (int i = threadIdx.x; i < DMODEL * 4; i += 256) srw[i] = ldf(rw, i, f32);
    __syncthreads();
    const int w = threadIdx.x >> 6, l = threadIdx.x & 63;
    const int t = blockIdx.x * 4 + w;
    double a0 = (double)ldf(rb, 0, f32), a1 = (double)ldf(rb, 1, f32);
    double a2 = (double)ldf(rb, 2, f32), a3 = (double)ldf(rb, 3, f32);
    const size_t xbase = (size_t)t * DMODEL + l * 8;
    #pragma unroll
    for (int j = 0; j < 8; ++j) {
        double xv = (double)ldf(xg, xbase + j, f32);
        int d = l * 8 + j;
        a0 += xv * (double)srw[d * 4 + 0];
        a1 += xv * (double)srw[d * 4 + 1];
        a2 += xv * (double)srw[d * 4 + 2];
        a3 += xv * (double)srw[d * 4 + 3];
    }
    #pragma unroll
    for (int off = 32; off > 0; off >>= 1) {
        a0 += __shfl_xor(a0, off);
        a1 += __shfl_xor(a1, off);
        a2 += __shfl_xor(a2, off);
        a3 += __shfl_xor(a3, off);
    }
    if (l == 0) {
        double mx = fmax(fmax(a0, a1), fmax(a2, a3));
        double e0 = exp(a0 - mx), e1 = exp(a1 - mx), e2 = exp(a2 - mx), e3 = exp(a3 - mx);
        double s = e0 + e1 + e2 + e3;
        float4 p = make_float4((float)(e0 / s), (float)(e1 / s),
                               (float)(e2 / s), (float)(e3 / s));
        *reinterpret_cast<float4*>(probs + (size_t)t * 4) = p;
    }
}

// ---------------------------------------------------------------------------
// Router phase B: per (batch, expert e=3,2,1) bitonic sort of u64 keys
// ((probbits<<32) | (2047-idx)) descending == (prob desc, idx asc).
__global__ __launch_bounds__(1024) void rsort_kernel(
    const float* __restrict__ probs, u16* __restrict__ sortedIdx)
{
    __shared__ u64 sk[NSEQ];   // 16 KB
    const int bid = blockIdx.x;
    const int b = bid / 3, ei = bid % 3, e = 3 - ei;
    const int tid = threadIdx.x;
    for (int n = tid; n < NSEQ; n += 1024) {
        unsigned fb = __float_as_uint(probs[((size_t)b * NSEQ + n) * 4 + e]);
        sk[n] = ((u64)fb << 32) | (unsigned)(2047 - n);
    }
    for (unsigned k = 2; k <= NSEQ; k <<= 1) {
        for (unsigned j = k >> 1; j > 0; j >>= 1) {
            __syncthreads();
            unsigned i = ((tid & ~(j - 1)) << 1) | (tid & (j - 1));
            unsigned ixj = i | j;
            u64 a = sk[i], c = sk[ixj];
            bool up = ((i & k) == 0);
            if ((a < c) == up) { sk[i] = c; sk[ixj] = a; }
        }
    }
    __syncthreads();
    u16* out = sortedIdx + ((size_t)b * 3 + ei) * NSEQ;
    for (int n = tid; n < NSEQ; n += 1024)
        out[n] = (u16)(2047u - (unsigned)(sk[n] & 0xFFFFFFFFu));
}

// ---------------------------------------------------------------------------
// Router phase C: greedy capacity selection per batch (e=3,2,1; leftovers->0),
// then emit dtok/rpw and the assigned/rp outputs.
__global__ __launch_bounds__(1024) void rassign_kernel(
    const float* __restrict__ probs, const u16* __restrict__ sortedIdx,
    const int* __restrict__ flag, int* __restrict__ dtok, float* __restrict__ rpw,
    void* __restrict__ outp)
{
    __shared__ int sassigned[NSEQ];   // 8 KB
    __shared__ int wsum[16];
    const int b = blockIdx.x;
    const int tid = threadIdx.x;
    const int lane = tid & 63;
    const bool f32 = (*flag != 0);
    for (int n = tid; n < NSEQ; n += 1024) sassigned[n] = -1;
    __syncthreads();
    const int caps[3] = {256, 256, 512};   // e = 3, 2, 1
    #pragma unroll
    for (int ei = 0; ei < 3; ++ei) {
        const int e = 3 - ei, cap = caps[ei];
        const u16* sl = sortedIdx + ((size_t)b * 3 + ei) * NSEQ;
        int t0 = sl[2 * tid], t1 = sl[2 * tid + 1];
        int f0 = (sassigned[t0] < 0) ? 1 : 0;
        int f1 = (sassigned[t1] < 0) ? 1 : 0;
        int s = f0 + f1;
        #pragma unroll
        for (int off = 1; off < 64; off <<= 1) {
            int v = __shfl_up(s, off);
            if (lane >= off) s += v;
        }
        if (lane == 63) wsum[tid >> 6] = s;
        __syncthreads();
        if (tid < 16) {
            int v = wsum[tid];
            #pragma unroll
            for (int off = 1; off < 16; off <<= 1) {
                int u = __shfl_up(v, off);
                if (tid >= off) v += u;
            }
            wsum[tid] = v;
        }
        __syncthreads();
        int wprev = (tid >> 6) ? wsum[(tid >> 6) - 1] : 0;
        int excl0 = s + wprev - f0 - f1;   // rank of t0 among unassigned
        if (f0 && excl0 < cap) sassigned[t0] = e;
        if (f1 && excl0 + f0 < cap) sassigned[t1] = e;
        __syncthreads();
    }
    const size_t base0 = (size_t)TOK * DMODEL;
    for (int n = tid; n < NSEQ; n += 1024) {
        int e = sassigned[n]; if (e < 0) e = 0;
        size_t g = (size_t)b * NSEQ + n;
        dtok[g] = 64 << e;
        float rpv = probs[g * 4 + e];
        rpw[g] = rpv;
        stf(outp, base0 + g, (float)e, f32);
        stf(outp, base0 + TOK + g, rpv, f32);
    }
}

// ---------------------------------------------------------------------------
// LayerNorm (+ nested mask). INMODE 0: input = native x; INMODE 1: fp32 z.
template <int INMODE>
__global__ __launch_bounds__(256) void ln_kernel(
    const void* __restrict__ in, const void* __restrict__ gw, const void* __restrict__ bw,
    const int* __restrict__ flag, const int* __restrict__ dtok, u16* __restrict__ out)
{
    const int row = blockIdx.x;
    const int tid = threadIdx.x;
    const bool f32 = (*flag != 0);
    size_t base = (size_t)row * DMODEL + tid * 2;
    float x0, x1;
    if (INMODE == 1 || f32) {
        float2 t = *(const float2*)((const float*)in + base);
        x0 = t.x; x1 = t.y;
    } else {
        const u16* p = (const u16*)in + base;
        x0 = bf2f(p[0]); x1 = bf2f(p[1]);
    }
    float s = x0 + x1;
    #pragma unroll
    for (int d2 = 32; d2 > 0; d2 >>= 1) s += __shfl_down(s, d2);
    __shared__ float red[4];
    if ((tid & 63) == 0) red[tid >> 6] = s;
    __syncthreads();
    s = red[0] + red[1] + red[2] + red[3];
    float mu = s * (1.0f / DMODEL);
    float d0 = x0 - mu, d1 = x1 - mu;
    float q2 = d0 * d0 + d1 * d1;
    #pragma unroll
    for (int d2 = 32; d2 > 0; d2 >>= 1) q2 += __shfl_down(q2, d2);
    __syncthreads();
    if ((tid & 63) == 0) red[tid >> 6] = q2;
    __syncthreads();
    q2 = red[0] + red[1] + red[2] + red[3];
    float inv = rsqrtf(q2 * (1.0f / DMODEL) + 1e-5f);
    int dt = dtok[row];
    int j0 = tid * 2;
    float r0 = (j0 < dt)     ? (d0 * inv * ldf(gw, j0, f32)     + ldf(bw, j0, f32))     : 0.0f;
    float r1 = (j0 + 1 < dt) ? (d1 * inv * ldf(gw, j0 + 1, f32) + ldf(bw, j0 + 1, f32)) : 0.0f;
    u16* op = out + (size_t)row * DMODEL + j0;
    op[0] = f2bf(r0); op[1] = f2bf(r1);
}

// ---------------------------------------------------------------------------
__device__ __forceinline__ float gelu_tanh(float x) {
    float x3 = x * x * x;
    float t = tanhf(0.7978845608028654f * (x + 0.044715f * x3));
    return 0.5f * x * (1.0f + t);
}

// MFMA GEMM: C[M,N] = A[M,K](bf16) @ B[K,N] with B given TRANSPOSED bf16 [N][K].
// 128x64 tile, 4 waves (2x2), 16 MFMA 16x16x32 per wave per K-64 step.
// Fragment pattern identical to the verified attn kernel (k-perm cancels).
// MODE 0: qkv  -> mask (c mod 512) < d_tok, write bf16
// MODE 1: oproj-> +bias, mask, + x residual, write fp32 z
// MODE 2: w1   -> +bias, mask c < 4*d_tok, gelu, write bf16 hid
// MODE 3: w2   -> +bias, mask, out = z + (1+alpha*rp)*val, write d_out (IO dtype)
template <int MODE>
__global__ __launch_bounds__(256) void mgemm_kernel(
    const u16* __restrict__ A, const u16* __restrict__ Bt, const void* __restrict__ bias,
    const int* __restrict__ flag, const int* __restrict__ dtok, const float* __restrict__ rp,
    const void* __restrict__ resx, const float* __restrict__ resz, const void* __restrict__ alp,
    void* __restrict__ C, float* __restrict__ Cz, int Ncols, int Kdim)
{
    __shared__ u16 As[128][72];   // 18 KB (144B rows, 16B aligned)
    __shared__ u16 Bs[64][72];    //  9 KB
    const int tid = threadIdx.x;
    const bool f32 = (*flag != 0);
    const int w = tid >> 6, l = tid & 63, ln = l & 15, lg = l >> 4;
    const int wr = w >> 1, wc = w & 1;
    const int m0 = blockIdx.x * 128, n0 = blockIdx.y * 64;

    f32x4 acc[4][2];
    #pragma unroll
    for (int mi = 0; mi < 4; ++mi)
        #pragma unroll
        for (int ci = 0; ci < 2; ++ci) acc[mi][ci] = f32x4{0.f, 0.f, 0.f, 0.f};

    const int ar = tid >> 1, ac = (tid & 1) * 32;
    const int br = tid >> 2, bc = (tid & 3) * 16;
    for (int k0 = 0; k0 < Kdim; k0 += 64) {
        __syncthreads();
        {
            const u16* src = A + (size_t)(m0 + ar) * Kdim + k0 + ac;
            uint4 v0 = *(const uint4*)(src);
            uint4 v1 = *(const uint4*)(src + 8);
            uint4 v2 = *(const uint4*)(src + 16);
            uint4 v3 = *(const uint4*)(src + 24);
            *(uint4*)&As[ar][ac]      = v0;
            *(uint4*)&As[ar][ac + 8]  = v1;
            *(uint4*)&As[ar][ac + 16] = v2;
            *(uint4*)&As[ar][ac + 24] = v3;
        }
        {
            const u16* src = Bt + (size_t)(n0 + br) * Kdim + k0 + bc;
            uint4 v0 = *(const uint4*)(src);
            uint4 v1 = *(const uint4*)(src + 8);
            *(uint4*)&Bs[br][bc]     = v0;
            *(uint4*)&Bs[br][bc + 8] = v1;
        }
        __syncthreads();
        bf16x8 fb[2][2];
        #pragma unroll
        for (int ci = 0; ci < 2; ++ci)
            #pragma unroll
            for (int ks = 0; ks < 2; ++ks)
                fb[ci][ks] = *reinterpret_cast<const bf16x8*>(
                    &Bs[wc * 32 + ci * 16 + ln][ks * 32 + lg * 8]);
        #pragma unroll
        for (int mi = 0; mi < 4; ++mi) {
            bf16x8 fa0 = *reinterpret_cast<const bf16x8*>(
                &As[wr * 64 + mi * 16 + ln][lg * 8]);
            bf16x8 fa1 = *reinterpret_cast<const bf16x8*>(
                &As[wr * 64 + mi * 16 + ln][32 + lg * 8]);
            acc[mi][0] = __builtin_amdgcn_mfma_f32_16x16x32_bf16(fa0, fb[0][0], acc[mi][0], 0, 0, 0);
            acc[mi][0] = __builtin_amdgcn_mfma_f32_16x16x32_bf16(fa1, fb[0][1], acc[mi][0], 0, 0, 0);
            acc[mi][1] = __builtin_amdgcn_mfma_f32_16x16x32_bf16(fa0, fb[1][0], acc[mi][1], 0, 0, 0);
            acc[mi][1] = __builtin_amdgcn_mfma_f32_16x16x32_bf16(fa1, fb[1][1], acc[mi][1], 0, 0, 0);
        }
    }

    const float alphav = (MODE == 3) ? ldf(alp, 0, f32) : 0.0f;
    #pragma unroll
    for (int mi = 0; mi < 4; ++mi) {
        #pragma unroll
        for (int r = 0; r < 4; ++r) {
            const int row = m0 + wr * 64 + mi * 16 + 4 * lg + r;
            const int dt = dtok[row];
            const float gate = (MODE == 3) ? (1.0f + alphav * rp[row]) : 0.0f;
            #pragma unroll
            for (int ci = 0; ci < 2; ++ci) {
                const int c = n0 + wc * 32 + ci * 16 + ln;
                float v = acc[mi][ci][r];
                if (MODE == 0) {
                    v = ((c & (DMODEL - 1)) < dt) ? v : 0.0f;
                    ((u16*)C)[(size_t)row * Ncols + c] = f2bf(v);
                } else if (MODE == 1) {
                    v += ldf(bias, c, f32);
                    if (c >= dt) v = 0.0f;
                    v += ldf(resx, (size_t)row * DMODEL + c, f32);
                    Cz[(size_t)row * DMODEL + c] = v;
                } else if (MODE == 2) {
                    v += ldf(bias, c, f32);
                    v = (c < 4 * dt) ? gelu_tanh(v) : 0.0f;
                    ((u16*)C)[(size_t)row * Ncols + c] = f2bf(v);
                } else {
                    v += ldf(bias, c, f32);
                    if (c >= dt) v = 0.0f;
                    float outv = resz[(size_t)row * DMODEL + c] + gate * v;
                    stf(C, (size_t)row * DMODEL + c, outv, f32);
                }
            }
        }
    }
}

// ---------------------------------------------------------------------------
// MFMA flash attention (16x16x32 bf16) — unchanged from round 4 (verified).
__global__ __launch_bounds__(256) void attn_kernel(
    const u16* __restrict__ qkv, const int* __restrict__ dtok, u16* __restrict__ o)
{
    __shared__ u16 Ks[64 * 72];
    __shared__ u16 Vs[64 * 76];
    __shared__ u16 Ps[4 * 16 * 72];

    const int bid = blockIdx.x;
    const int qblk = bid & 31, hh = (bid >> 5) & 7, b = bid >> 8;
    const int tid = threadIdx.x;
    const int w = tid >> 6, l = tid & 63;
    const int ln = l & 15, lg = l >> 4;

    const size_t bbase = (size_t)b * NSEQ;
    const int q0 = qblk * 64 + w * 16;

    bf16x8 qa[2];
    {
        const u16* qrow = qkv + (bbase + q0 + ln) * 1536 + hh * 64;
        #pragma unroll
        for (int s = 0; s < 2; ++s) {
            bf16x8 t = *reinterpret_cast<const bf16x8*>(qrow + 8 * lg + 32 * s);
            #pragma unroll
            for (int j = 0; j < 8; ++j) t[j] = (__bf16)((float)t[j] * 0.125f);
            qa[s] = t;
        }
    }

    f32x4 oacc[4];
    #pragma unroll
    for (int d0 = 0; d0 < 4; ++d0) oacc[d0] = f32x4{0.f, 0.f, 0.f, 0.f};
    float mold[4] = {-INFINITY, -INFINITY, -INFINITY, -INFINITY};
    float lsum[4] = {0.f, 0.f, 0.f, 0.f};
    u16* Pw = Ps + w * 16 * 72;

    for (int t0 = 0; t0 < NSEQ; t0 += 64) {
        __syncthreads();
        #pragma unroll
        for (int p = 0; p < 2; ++p) {
            int idx = p * 256 + tid;
            int row = idx >> 3, c8 = (idx & 7) * 8;
            const u16* src = qkv + (bbase + t0 + row) * 1536 + 512 + hh * 64 + c8;
            uint4 kv = *reinterpret_cast<const uint4*>(src);
            *reinterpret_cast<uint4*>(&Ks[row * 72 + c8]) = kv;
            uint4 vv = *reinterpret_cast<const uint4*>(src + 512);
            *reinterpret_cast<uint2*>(&Vs[row * 76 + c8]) = make_uint2(vv.x, vv.y);
            *reinterpret_cast<uint2*>(&Vs[row * 76 + c8 + 4]) = make_uint2(vv.z, vv.w);
        }
        __syncthreads();

        f32x4 sa[4];
        #pragma unroll
        for (int kb = 0; kb < 4; ++kb) sa[kb] = f32x4{0.f, 0.f, 0.f, 0.f};
        #pragma unroll
        for (int kb = 0; kb < 4; ++kb) {
            #pragma unroll
            for (int s = 0; s < 2; ++s) {
                bf16x8 kf = *reinterpret_cast<const bf16x8*>(
                    &Ks[(kb * 16 + ln) * 72 + 8 * lg + 32 * s]);
                sa[kb] = __builtin_amdgcn_mfma_f32_16x16x32_bf16(qa[s], kf, sa[kb], 0, 0, 0);
            }
        }

        float nm[4], sc[4];
        #pragma unroll
        for (int r = 0; r < 4; ++r) {
            float mx = fmaxf(fmaxf(sa[0][r], sa[1][r]), fmaxf(sa[2][r], sa[3][r]));
            mx = fmaxf(mx, __shfl_xor(mx, 1));
            mx = fmaxf(mx, __shfl_xor(mx, 2));
            mx = fmaxf(mx, __shfl_xor(mx, 4));
            mx = fmaxf(mx, __shfl_xor(mx, 8));
            nm[r] = fmaxf(mold[r], mx);
            sc[r] = __expf(mold[r] - nm[r]);
            mold[r] = nm[r];
        }
        float psum[4] = {0.f, 0.f, 0.f, 0.f};
        #pragma unroll
        for (int kb = 0; kb < 4; ++kb) {
            #pragma unroll
            for (int r = 0; r < 4; ++r) {
                float p = __expf(sa[kb][r] - nm[r]);
                psum[r] += p;
                Pw[(4 * lg + r) * 72 + kb * 16 + ln] = f2bf(p);
            }
        }
        #pragma unroll
        for (int r = 0; r < 4; ++r) {
            float s = psum[r];
            s += __shfl_xor(s, 1);
            s += __shfl_xor(s, 2);
            s += __shfl_xor(s, 4);
            s += __shfl_xor(s, 8);
            lsum[r] = lsum[r] * sc[r] + s;
            #pragma unroll
            for (int d0 = 0; d0 < 4; ++d0) oacc[d0][r] *= sc[r];
        }
        asm volatile("s_waitcnt lgkmcnt(0)" ::: "memory");

        #pragma unroll
        for (int d0 = 0; d0 < 4; ++d0) {
            #pragma unroll
            for (int s = 0; s < 2; ++s) {
                bf16x8 pf = *reinterpret_cast<const bf16x8*>(
                    &Pw[ln * 72 + 8 * lg + 32 * s]);
                bf16x8 vf;
                #pragma unroll
                for (int j = 0; j < 8; ++j) {
                    union { u16 u; __bf16 y; } cv;
                    cv.u = Vs[(8 * lg + 32 * s + j) * 76 + d0 * 16 + ln];
                    vf[j] = cv.y;
                }
                oacc[d0] = __builtin_amdgcn_mfma_f32_16x16x32_bf16(pf, vf, oacc[d0], 0, 0, 0);
            }
        }
    }

    #pragma unroll
    for (int r = 0; r < 4; ++r) {
        int qrow = q0 + 4 * lg + r;
        bool elig = dtok[bbase + qrow] > hh * 64;
        float rinv = elig ? (1.0f / lsum[r]) : 0.0f;
        u16* obp = o + (bbase + qrow) * DMODEL + hh * 64;
        #pragma unroll
        for (int d0 = 0; d0 < 4; ++d0)
            obp[d0 * 16 + ln] = f2bf(oacc[d0][r] * rinv);
    }
}

// ---------------------------------------------------------------------------
extern "C" void kernel_launch(void* const* d_in, const int* in_sizes, int n_in,
                              void* d_out, int out_size, void* d_ws, size_t ws_size,
                              hipStream_t stream)
{
    (void)in_sizes; (void)n_in; (void)out_size; (void)ws_size;
    const void* x    = d_in[0];
    const void* r_w  = d_in[1];
    const void* r_b  = d_in[2];
    const void* g1   = d_in[3];
    const void* b1   = d_in[4];
    const void* g2   = d_in[5];
    const void* b2   = d_in[6];
    const void* wqkv = d_in[7];
    const void* wo   = d_in[8];
    const void* bo   = d_in[9];
    const void* w1   = d_in[10];
    const void* b1f  = d_in[11];
    const void* w2   = d_in[12];
    const void* b2f  = d_in[13];
    const void* alp  = d_in[14];

    // Workspace overlay (~63.3 MB):
    //   [0,8M)    h / hm (bf16)
    //   [8M,32M)  qkv (bf16); later z (fp32) @ [8M,24M)
    //   [24M,56M) hid (bf16)  (after qkv dead)
    //   [32M,40M) ob (bf16)   (between attn and gemm1; inside hid's future range)
    //   [56M,62M) bf16 transposed weights
    //   [63M,..)  meta: flag, dtok, rpw, probs, sortedIdx
    const size_t MB = 1024 * 1024;
    char* ws = (char*)d_ws;
    u16*   h      = (u16*)  (ws);
    u16*   hm     = (u16*)  (ws);
    u16*   qkv    = (u16*)  (ws + 8 * MB);
    float* z      = (float*)(ws + 8 * MB);
    u16*   hid    = (u16*)  (ws + 24 * MB);
    u16*   ob     = (u16*)  (ws + 32 * MB);
    u16*   wqkvT  = (u16*)  (ws + 56 * MB);                 // [1536][512]
    u16*   woT    = (u16*)  (ws + 56 * MB + 1572864);       // [512][512]
    u16*   w1T    = (u16*)  (ws + 56 * MB + 2097152);       // [2048][512]
    u16*   w2T    = (u16*)  (ws + 56 * MB + 4194304);       // [512][2048]
    int*   flag   = (int*)  (ws + 63 * MB);
    int*   dtok   = (int*)  (ws + 63 * MB + 1024);
    float* rpw    = (float*)(ws + 63 * MB + 1024 + 32768);
    float* probs  = (float*)(ws + 63 * MB + 1024 + 65536);          // [TOK][4]
    u16*   sorted = (u16*)  (ws + 63 * MB + 1024 + 65536 + 131072); // [B][3][2048]

    detect_kernel<<<1, 256, 0, stream>>>((const u16*)x, flag);
    wconv_kernel<<<dim3(16, 48), 256, 0, stream>>>(wqkv, flag, wqkvT, 512, 1536);
    wconv_kernel<<<dim3(16, 16), 256, 0, stream>>>(wo,   flag, woT,   512, 512);
    wconv_kernel<<<dim3(16, 64), 256, 0, stream>>>(w1,   flag, w1T,   512, 2048);
    wconv_kernel<<<dim3(64, 16), 256, 0, stream>>>(w2,   flag, w2T,   2048, 512);
    rprob_kernel<<<TOK / 4, 256, 0, stream>>>(x, r_w, r_b, flag, probs);
    rsort_kernel<<<BATCH * 3, 1024, 0, stream>>>(probs, sorted);
    rassign_kernel<<<BATCH, 1024, 0, stream>>>(probs, sorted, flag, dtok, rpw, d_out);
    ln_kernel<0><<<TOK, 256, 0, stream>>>(x, g1, b1, flag, dtok, h);
    mgemm_kernel<0><<<dim3(TOK / 128, 1536 / 64), 256, 0, stream>>>(
        h, wqkvT, nullptr, flag, dtok, nullptr, nullptr, nullptr, nullptr,
        qkv, nullptr, 1536, 512);
    attn_kernel<<<BATCH * 8 * (NSEQ / 64), 256, 0, stream>>>(qkv, dtok, ob);
    mgemm_kernel<1><<<dim3(TOK / 128, 512 / 64), 256, 0, stream>>>(
        ob, woT, bo, flag, dtok, nullptr, x, nullptr, nullptr,
        nullptr, z, 512, 512);
    ln_kernel<1><<<TOK, 256, 0, stream>>>(z, g2, b2, flag, dtok, hm);
    mgemm_kernel<2><<<dim3(TOK / 128, 2048 / 64), 256, 0, stream>>>(
        hm, w1T, b1f, flag, dtok, nullptr, nullptr, nullptr, nullptr,
        hid, nullptr, 2048, 512);
    mgemm_kernel<3><<<dim3(TOK / 128, 512 / 64), 256, 0, stream>>>(
        hid, w2T, b2f, flag, dtok, rpw, nullptr, z, alp,
        d_out, nullptr, 512, 2048);
}

// Round 6
// 339.628 us; speedup vs baseline: 18.1894x; 1.0578x over previous
//
#include <hip/hip_runtime.h>

typedef unsigned short u16;
typedef unsigned long long u64;

#define BATCH  4
#define NSEQ   2048
#define DMODEL 512
#define TOK    8192   // BATCH*NSEQ

typedef __attribute__((ext_vector_type(8))) __bf16 bf16x8;
typedef __attribute__((ext_vector_type(4))) float f32x4;

__device__ __forceinline__ float bf2f(u16 u) {
    unsigned int x = ((unsigned int)u) << 16;
    return __uint_as_float(x);
}
__device__ __forceinline__ u16 f2bf(float f) {
    unsigned int x = __float_as_uint(f);
    unsigned int r = (x + 0x7FFFu + ((x >> 16) & 1u)) >> 16;  // RNE
    return (u16)r;
}
// dual-dtype load: flag!=0 -> input tensors are fp32, else bf16
__device__ __forceinline__ float ldf(const void* p, size_t i, bool f32) {
    return f32 ? ((const float*)p)[i] : bf2f(((const u16*)p)[i]);
}
// dual-dtype store to d_out (IO dtypes are coupled: fp32 in => fp32 out)
__device__ __forceinline__ void stf(void* p, size_t i, float v, bool f32) {
    if (f32) ((float*)p)[i] = v;
    else     ((u16*)p)[i] = f2bf(v);
}

// ---------------------------------------------------------------------------
// Input dtype detection (fp32 confirmed by round 3; kept for robustness).
__global__ void detect_kernel(const u16* __restrict__ x, int* __restrict__ flag) {
    __shared__ int cnt;
    if (threadIdx.x == 0) cnt = 0;
    __syncthreads();
    int sane = 0;
    for (int i = threadIdx.x; i < 2048; i += blockDim.x) {
        u16 u = x[2 * i];
        int e = (u >> 7) & 0xFF;
        if (u == 0 || (e >= 100 && e <= 140)) sane++;
    }
    atomicAdd(&cnt, sane);
    __syncthreads();
    if (threadIdx.x == 0) *flag = (cnt >= 1024) ? 0 : 1;  // 1 => fp32 inputs
}

// ---------------------------------------------------------------------------
// Weight convert + transpose: in (native) [K][N] -> out bf16 [N][K].
__global__ __launch_bounds__(256) void wconv_kernel(
    const void* __restrict__ in, const int* __restrict__ flag,
    u16* __restrict__ out, int K, int N)
{
    __shared__ float t[32][33];
    const bool f32 = (*flag != 0);
    const int kb = blockIdx.x * 32, nb = blockIdx.y * 32;
    const int tx = threadIdx.x & 7, ty = threadIdx.x >> 3;
    #pragma unroll
    for (int i = 0; i < 4; ++i)
        t[ty][tx * 4 + i] = ldf(in, (size_t)(kb + ty) * N + nb + tx * 4 + i, f32);
    __syncthreads();
    #pragma unroll
    for (int i = 0; i < 4; ++i)
        out[(size_t)(nb + ty) * K + kb + tx * 4 + i] = f2bf(t[tx * 4 + i][ty]);
}

// ---------------------------------------------------------------------------
// Router phase A: fp64 logits + softmax, one wave per token.
__global__ __launch_bounds__(256) void rprob_kernel(
    const void* __restrict__ xg, const void* __restrict__ rw, const void* __restrict__ rb,
    const int* __restrict__ flag, float* __restrict__ probs)
{
    __shared__ float srw[DMODEL * 4];
    const bool f32 = (*flag != 0);
    for (int i = threadIdx.x; i < DMODEL * 4; i += 256) srw[i] = ldf(rw, i, f32);
    __syncthreads();
    const int w = threadIdx.x >> 6, l = threadIdx.x & 63;
    const int t = blockIdx.x * 4 + w;
    double a0 = (double)ldf(rb, 0, f32), a1 = (double)ldf(rb, 1, f32);
    double a2 = (double)ldf(rb, 2, f32), a3 = (double)ldf(rb, 3, f32);
    const size_t xbase = (size_t)t * DMODEL + l * 8;
    #pragma unroll
    for (int j = 0; j < 8; ++j) {
        double xv = (double)ldf(xg, xbase + j, f32);
        int d = l * 8 + j;
        a0 += xv * (double)srw[d * 4 + 0];
        a1 += xv * (double)srw[d * 4 + 1];
        a2 += xv * (double)srw[d * 4 + 2];
        a3 += xv * (double)srw[d * 4 + 3];
    }
    #pragma unroll
    for (int off = 32; off > 0; off >>= 1) {
        a0 += __shfl_xor(a0, off);
        a1 += __shfl_xor(a1, off);
        a2 += __shfl_xor(a2, off);
        a3 += __shfl_xor(a3, off);
    }
    if (l == 0) {
        double mx = fmax(fmax(a0, a1), fmax(a2, a3));
        double e0 = exp(a0 - mx), e1 = exp(a1 - mx), e2 = exp(a2 - mx), e3 = exp(a3 - mx);
        double s = e0 + e1 + e2 + e3;
        float4 p = make_float4((float)(e0 / s), (float)(e1 / s),
                               (float)(e2 / s), (float)(e3 / s));
        *reinterpret_cast<float4*>(probs + (size_t)t * 4) = p;
    }
}

// ---------------------------------------------------------------------------
// Router phase B: per (batch, expert e=3,2,1) bitonic sort of u64 keys
// ((probbits<<32) | (2047-idx)) descending == (prob desc, idx asc).
__global__ __launch_bounds__(1024) void rsort_kernel(
    const float* __restrict__ probs, u16* __restrict__ sortedIdx)
{
    __shared__ u64 sk[NSEQ];   // 16 KB
    const int bid = blockIdx.x;
    const int b = bid / 3, ei = bid % 3, e = 3 - ei;
    const int tid = threadIdx.x;
    for (int n = tid; n < NSEQ; n += 1024) {
        unsigned fb = __float_as_uint(probs[((size_t)b * NSEQ + n) * 4 + e]);
        sk[n] = ((u64)fb << 32) | (unsigned)(2047 - n);
    }
    for (unsigned k = 2; k <= NSEQ; k <<= 1) {
        for (unsigned j = k >> 1; j > 0; j >>= 1) {
            __syncthreads();
            unsigned i = ((tid & ~(j - 1)) << 1) | (tid & (j - 1));
            unsigned ixj = i | j;
            u64 a = sk[i], c = sk[ixj];
            bool up = ((i & k) == 0);
            if ((a < c) == up) { sk[i] = c; sk[ixj] = a; }
        }
    }
    __syncthreads();
    u16* out = sortedIdx + ((size_t)b * 3 + ei) * NSEQ;
    for (int n = tid; n < NSEQ; n += 1024)
        out[n] = (u16)(2047u - (unsigned)(sk[n] & 0xFFFFFFFFu));
}

// ---------------------------------------------------------------------------
// Router phase C: greedy capacity selection per batch (e=3,2,1; leftovers->0),
// emit dtok/rpw/outputs AND the deterministic expert-sorted permutation
// perm[b] = [e3 tokens (256) | e2 (256) | e1 (512) | e0 (1024)], each group
// in ascending token order (stable block-scan ranks).
__global__ __launch_bounds__(1024) void rassign_kernel(
    const float* __restrict__ probs, const u16* __restrict__ sortedIdx,
    const int* __restrict__ flag, int* __restrict__ dtok, float* __restrict__ rpw,
    int* __restrict__ perm, void* __restrict__ outp)
{
    __shared__ int sassigned[NSEQ];   // 8 KB
    __shared__ int wsum[16];
    const int b = blockIdx.x;
    const int tid = threadIdx.x;
    const int lane = tid & 63;
    const bool f32 = (*flag != 0);
    for (int n = tid; n < NSEQ; n += 1024) sassigned[n] = -1;
    __syncthreads();
    const int caps[3] = {256, 256, 512};   // e = 3, 2, 1
    #pragma unroll
    for (int ei = 0; ei < 3; ++ei) {
        const int e = 3 - ei, cap = caps[ei];
        const u16* sl = sortedIdx + ((size_t)b * 3 + ei) * NSEQ;
        int t0 = sl[2 * tid], t1 = sl[2 * tid + 1];
        int f0 = (sassigned[t0] < 0) ? 1 : 0;
        int f1 = (sassigned[t1] < 0) ? 1 : 0;
        int s = f0 + f1;
        #pragma unroll
        for (int off = 1; off < 64; off <<= 1) {
            int v = __shfl_up(s, off);
            if (lane >= off) s += v;
        }
        if (lane == 63) wsum[tid >> 6] = s;
        __syncthreads();
        if (tid < 16) {
            int v = wsum[tid];
            #pragma unroll
            for (int off = 1; off < 16; off <<= 1) {
                int u = __shfl_up(v, off);
                if (tid >= off) v += u;
            }
            wsum[tid] = v;
        }
        __syncthreads();
        int wprev = (tid >> 6) ? wsum[(tid >> 6) - 1] : 0;
        int excl0 = s + wprev - f0 - f1;   // rank of t0 among unassigned
        if (f0 && excl0 < cap) sassigned[t0] = e;
        if (f1 && excl0 + f0 < cap) sassigned[t1] = e;
        __syncthreads();
    }
    // leftovers -> expert 0
    for (int n = tid; n < NSEQ; n += 1024)
        if (sassigned[n] < 0) sassigned[n] = 0;
    __syncthreads();
    // stable perm: for each expert, block-scan rank in ascending token order
    #pragma unroll
    for (int e = 0; e < 4; ++e) {
        const int n0 = 2 * tid, n1 = 2 * tid + 1;
        const int f0 = (sassigned[n0] == e) ? 1 : 0;
        const int f1 = (sassigned[n1] == e) ? 1 : 0;
        int s = f0 + f1;
        #pragma unroll
        for (int off = 1; off < 64; off <<= 1) {
            int v = __shfl_up(s, off);
            if (lane >= off) s += v;
        }
        if (lane == 63) wsum[tid >> 6] = s;
        __syncthreads();
        if (tid < 16) {
            int v = wsum[tid];
            #pragma unroll
            for (int off = 1; off < 16; off <<= 1) {
                int u = __shfl_up(v, off);
                if (tid >= off) v += u;
            }
            wsum[tid] = v;
        }
        __syncthreads();
        int wprev = (tid >> 6) ? wsum[(tid >> 6) - 1] : 0;
        int rank0 = s + wprev - f0 - f1;
        const int offe = (e == 3) ? 0 : (e == 2) ? 256 : (e == 1) ? 512 : 1024;
        if (f0) perm[b * NSEQ + offe + rank0] = n0;
        if (f1) perm[b * NSEQ + offe + rank0 + f0] = n1;
        __syncthreads();
    }
    const size_t base0 = (size_t)TOK * DMODEL;
    for (int n = tid; n < NSEQ; n += 1024) {
        int e = sassigned[n];
        size_t g = (size_t)b * NSEQ + n;
        dtok[g] = 64 << e;
        float rpv = probs[g * 4 + e];
        rpw[g] = rpv;
        stf(outp, base0 + g, (float)e, f32);
        stf(outp, base0 + TOK + g, rpv, f32);
    }
}

// ---------------------------------------------------------------------------
// LayerNorm (+ nested mask). INMODE 0: input = native x; INMODE 1: fp32 z.
template <int INMODE>
__global__ __launch_bounds__(256) void ln_kernel(
    const void* __restrict__ in, const void* __restrict__ gw, const void* __restrict__ bw,
    const int* __restrict__ flag, const int* __restrict__ dtok, u16* __restrict__ out)
{
    const int row = blockIdx.x;
    const int tid = threadIdx.x;
    const bool f32 = (*flag != 0);
    size_t base = (size_t)row * DMODEL + tid * 2;
    float x0, x1;
    if (INMODE == 1 || f32) {
        float2 t = *(const float2*)((const float*)in + base);
        x0 = t.x; x1 = t.y;
    } else {
        const u16* p = (const u16*)in + base;
        x0 = bf2f(p[0]); x1 = bf2f(p[1]);
    }
    float s = x0 + x1;
    #pragma unroll
    for (int d2 = 32; d2 > 0; d2 >>= 1) s += __shfl_down(s, d2);
    __shared__ float red[4];
    if ((tid & 63) == 0) red[tid >> 6] = s;
    __syncthreads();
    s = red[0] + red[1] + red[2] + red[3];
    float mu = s * (1.0f / DMODEL);
    float d0 = x0 - mu, d1 = x1 - mu;
    float q2 = d0 * d0 + d1 * d1;
    #pragma unroll
    for (int d2 = 32; d2 > 0; d2 >>= 1) q2 += __shfl_down(q2, d2);
    __syncthreads();
    if ((tid & 63) == 0) red[tid >> 6] = q2;
    __syncthreads();
    q2 = red[0] + red[1] + red[2] + red[3];
    float inv = rsqrtf(q2 * (1.0f / DMODEL) + 1e-5f);
    int dt = dtok[row];
    int j0 = tid * 2;
    float r0 = (j0 < dt)     ? (d0 * inv * ldf(gw, j0, f32)     + ldf(bw, j0, f32))     : 0.0f;
    float r1 = (j0 + 1 < dt) ? (d1 * inv * ldf(gw, j0 + 1, f32) + ldf(bw, j0 + 1, f32)) : 0.0f;
    u16* op = out + (size_t)row * DMODEL + j0;
    op[0] = f2bf(r0); op[1] = f2bf(r1);
}

// ---------------------------------------------------------------------------
__device__ __forceinline__ float gelu_tanh(float x) {
    float x3 = x * x * x;
    float t = tanhf(0.7978845608028654f * (x + 0.044715f * x3));
    return 0.5f * x * (1.0f + t);
}

// MFMA GEMM: C[M,N] = A[M,K](bf16) @ B[K,N] with B given TRANSPOSED bf16 [N][K].
// 128x64 tile, 4 waves (2x2), 16 MFMA 16x16x32 per wave per K-64 step.
// MODE 0: qkv  -> mask (c mod 512) < d_tok, write bf16
// MODE 1: oproj-> +bias, mask, + x residual, write fp32 z
// MODE 2: w1   -> +bias, mask c < 4*d_tok, gelu, write bf16 hid
// MODE 3: w2   -> +bias, mask, out = z + (1+alpha*rp)*val, write d_out (IO dtype)
template <int MODE>
__global__ __launch_bounds__(256) void mgemm_kernel(
    const u16* __restrict__ A, const u16* __restrict__ Bt, const void* __restrict__ bias,
    const int* __restrict__ flag, const int* __restrict__ dtok, const float* __restrict__ rp,
    const void* __restrict__ resx, const float* __restrict__ resz, const void* __restrict__ alp,
    void* __restrict__ C, float* __restrict__ Cz, int Ncols, int Kdim)
{
    __shared__ u16 As[128][72];   // 18 KB (144B rows, 16B aligned)
    __shared__ u16 Bs[64][72];    //  9 KB
    const int tid = threadIdx.x;
    const bool f32 = (*flag != 0);
    const int w = tid >> 6, l = tid & 63, ln = l & 15, lg = l >> 4;
    const int wr = w >> 1, wc = w & 1;
    const int m0 = blockIdx.x * 128, n0 = blockIdx.y * 64;

    f32x4 acc[4][2];
    #pragma unroll
    for (int mi = 0; mi < 4; ++mi)
        #pragma unroll
        for (int ci = 0; ci < 2; ++ci) acc[mi][ci] = f32x4{0.f, 0.f, 0.f, 0.f};

    const int ar = tid >> 1, ac = (tid & 1) * 32;
    const int br = tid >> 2, bc = (tid & 3) * 16;
    for (int k0 = 0; k0 < Kdim; k0 += 64) {
        __syncthreads();
        {
            const u16* src = A + (size_t)(m0 + ar) * Kdim + k0 + ac;
            uint4 v0 = *(const uint4*)(src);
            uint4 v1 = *(const uint4*)(src + 8);
            uint4 v2 = *(const uint4*)(src + 16);
            uint4 v3 = *(const uint4*)(src + 24);
            *(uint4*)&As[ar][ac]      = v0;
            *(uint4*)&As[ar][ac + 8]  = v1;
            *(uint4*)&As[ar][ac + 16] = v2;
            *(uint4*)&As[ar][ac + 24] = v3;
        }
        {
            const u16* src = Bt + (size_t)(n0 + br) * Kdim + k0 + bc;
            uint4 v0 = *(const uint4*)(src);
            uint4 v1 = *(const uint4*)(src + 8);
            *(uint4*)&Bs[br][bc]     = v0;
            *(uint4*)&Bs[br][bc + 8] = v1;
        }
        __syncthreads();
        bf16x8 fb[2][2];
        #pragma unroll
        for (int ci = 0; ci < 2; ++ci)
            #pragma unroll
            for (int ks = 0; ks < 2; ++ks)
                fb[ci][ks] = *reinterpret_cast<const bf16x8*>(
                    &Bs[wc * 32 + ci * 16 + ln][ks * 32 + lg * 8]);
        #pragma unroll
        for (int mi = 0; mi < 4; ++mi) {
            bf16x8 fa0 = *reinterpret_cast<const bf16x8*>(
                &As[wr * 64 + mi * 16 + ln][lg * 8]);
            bf16x8 fa1 = *reinterpret_cast<const bf16x8*>(
                &As[wr * 64 + mi * 16 + ln][32 + lg * 8]);
            acc[mi][0] = __builtin_amdgcn_mfma_f32_16x16x32_bf16(fa0, fb[0][0], acc[mi][0], 0, 0, 0);
            acc[mi][0] = __builtin_amdgcn_mfma_f32_16x16x32_bf16(fa1, fb[0][1], acc[mi][0], 0, 0, 0);
            acc[mi][1] = __builtin_amdgcn_mfma_f32_16x16x32_bf16(fa0, fb[1][0], acc[mi][1], 0, 0, 0);
            acc[mi][1] = __builtin_amdgcn_mfma_f32_16x16x32_bf16(fa1, fb[1][1], acc[mi][1], 0, 0, 0);
        }
    }

    const float alphav = (MODE == 3) ? ldf(alp, 0, f32) : 0.0f;
    #pragma unroll
    for (int mi = 0; mi < 4; ++mi) {
        #pragma unroll
        for (int r = 0; r < 4; ++r) {
            const int row = m0 + wr * 64 + mi * 16 + 4 * lg + r;
            const int dt = dtok[row];
            const float gate = (MODE == 3) ? (1.0f + alphav * rp[row]) : 0.0f;
            #pragma unroll
            for (int ci = 0; ci < 2; ++ci) {
                const int c = n0 + wc * 32 + ci * 16 + ln;
                float v = acc[mi][ci][r];
                if (MODE == 0) {
                    v = ((c & (DMODEL - 1)) < dt) ? v : 0.0f;
                    ((u16*)C)[(size_t)row * Ncols + c] = f2bf(v);
                } else if (MODE == 1) {
                    v += ldf(bias, c, f32);
                    if (c >= dt) v = 0.0f;
                    v += ldf(resx, (size_t)row * DMODEL + c, f32);
                    Cz[(size_t)row * DMODEL + c] = v;
                } else if (MODE == 2) {
                    v += ldf(bias, c, f32);
                    v = (c < 4 * dt) ? gelu_tanh(v) : 0.0f;
                    ((u16*)C)[(size_t)row * Ncols + c] = f2bf(v);
                } else {
                    v += ldf(bias, c, f32);
                    if (c >= dt) v = 0.0f;
                    float outv = resz[(size_t)row * DMODEL + c] + gate * v;
                    stf(C, (size_t)row * DMODEL + c, outv, f32);
                }
            }
        }
    }
}

// ---------------------------------------------------------------------------
// MFMA flash attention over expert-compacted eligible sets.
// Per head h, eligible tokens = first C_h entries of perm (d_tok > 64h); both
// query rows and key/value rows are gathered through perm. The 2048-C_h
// ineligible keys have score exactly 0 and V=0, folded in analytically:
// M = max(m,0), l += (2048-C_h)*exp(-M). Ineligible query rows are never
// written (ob pre-zeroed).
__global__ __launch_bounds__(256) void attn_kernel(
    const u16* __restrict__ qkv, const int* __restrict__ perm, u16* __restrict__ o)
{
    __shared__ u16 Ks[64 * 72];
    __shared__ u16 Vs[64 * 76];
    __shared__ u16 Ps[4 * 16 * 72];

    const int bid = blockIdx.x;
    const int b = bid / 80;
    const int rr = bid % 80;
    int hh, qc, C;
    if (rr < 32)      { hh = 0; qc = rr;      C = 2048; }
    else if (rr < 48) { hh = 1; qc = rr - 32; C = 1024; }
    else if (rr < 56) { hh = 2; qc = rr - 48; C = 512;  }
    else if (rr < 64) { hh = 3; qc = rr - 56; C = 512;  }
    else { hh = 4 + ((rr - 64) >> 2); qc = (rr - 64) & 3; C = 256; }

    const int tid = threadIdx.x;
    const int w = tid >> 6, l = tid & 63;
    const int ln = l & 15, lg = l >> 4;

    const size_t bbase = (size_t)b * NSEQ;
    const int* pb = perm + b * NSEQ;
    const int q0 = qc * 64 + w * 16;

    // Q fragments (perm-gathered rows), pre-scaled by 1/8 (exact in bf16)
    bf16x8 qa[2];
    {
        const int qtok = pb[q0 + ln];
        const u16* qrow = qkv + (bbase + qtok) * 1536 + hh * 64;
        #pragma unroll
        for (int s = 0; s < 2; ++s) {
            bf16x8 t = *reinterpret_cast<const bf16x8*>(qrow + 8 * lg + 32 * s);
            #pragma unroll
            for (int j = 0; j < 8; ++j) t[j] = (__bf16)((float)t[j] * 0.125f);
            qa[s] = t;
        }
    }

    f32x4 oacc[4];
    #pragma unroll
    for (int d0 = 0; d0 < 4; ++d0) oacc[d0] = f32x4{0.f, 0.f, 0.f, 0.f};
    float mold[4] = {-INFINITY, -INFINITY, -INFINITY, -INFINITY};
    float lsum[4] = {0.f, 0.f, 0.f, 0.f};
    u16* Pw = Ps + w * 16 * 72;

    for (int t0 = 0; t0 < C; t0 += 64) {
        __syncthreads();
        #pragma unroll
        for (int p = 0; p < 2; ++p) {
            int idx = p * 256 + tid;
            int row = idx >> 3, c8 = (idx & 7) * 8;
            const int ktok = pb[t0 + row];
            const u16* src = qkv + (bbase + ktok) * 1536 + 512 + hh * 64 + c8;
            uint4 kv = *reinterpret_cast<const uint4*>(src);
            *reinterpret_cast<uint4*>(&Ks[row * 72 + c8]) = kv;
            uint4 vv = *reinterpret_cast<const uint4*>(src + 512);
            *reinterpret_cast<uint2*>(&Vs[row * 76 + c8]) = make_uint2(vv.x, vv.y);
            *reinterpret_cast<uint2*>(&Vs[row * 76 + c8 + 4]) = make_uint2(vv.z, vv.w);
        }
        __syncthreads();

        f32x4 sa[4];
        #pragma unroll
        for (int kb = 0; kb < 4; ++kb) sa[kb] = f32x4{0.f, 0.f, 0.f, 0.f};
        #pragma unroll
        for (int kb = 0; kb < 4; ++kb) {
            #pragma unroll
            for (int s = 0; s < 2; ++s) {
                bf16x8 kf = *reinterpret_cast<const bf16x8*>(
                    &Ks[(kb * 16 + ln) * 72 + 8 * lg + 32 * s]);
                sa[kb] = __builtin_amdgcn_mfma_f32_16x16x32_bf16(qa[s], kf, sa[kb], 0, 0, 0);
            }
        }

        float nm[4], sc[4];
        #pragma unroll
        for (int r = 0; r < 4; ++r) {
            float mx = fmaxf(fmaxf(sa[0][r], sa[1][r]), fmaxf(sa[2][r], sa[3][r]));
            mx = fmaxf(mx, __shfl_xor(mx, 1));
            mx = fmaxf(mx, __shfl_xor(mx, 2));
            mx = fmaxf(mx, __shfl_xor(mx, 4));
            mx = fmaxf(mx, __shfl_xor(mx, 8));
            nm[r] = fmaxf(mold[r], mx);
            sc[r] = __expf(mold[r] - nm[r]);
            mold[r] = nm[r];
        }
        float psum[4] = {0.f, 0.f, 0.f, 0.f};
        #pragma unroll
        for (int kb = 0; kb < 4; ++kb) {
            #pragma unroll
            for (int r = 0; r < 4; ++r) {
                float p = __expf(sa[kb][r] - nm[r]);
                psum[r] += p;
                Pw[(4 * lg + r) * 72 + kb * 16 + ln] = f2bf(p);
            }
        }
        #pragma unroll
        for (int r = 0; r < 4; ++r) {
            float s = psum[r];
            s += __shfl_xor(s, 1);
            s += __shfl_xor(s, 2);
            s += __shfl_xor(s, 4);
            s += __shfl_xor(s, 8);
            lsum[r] = lsum[r] * sc[r] + s;
            #pragma unroll
            for (int d0 = 0; d0 < 4; ++d0) oacc[d0][r] *= sc[r];
        }
        asm volatile("s_waitcnt lgkmcnt(0)" ::: "memory");

        #pragma unroll
        for (int d0 = 0; d0 < 4; ++d0) {
            #pragma unroll
            for (int s = 0; s < 2; ++s) {
                bf16x8 pf = *reinterpret_cast<const bf16x8*>(
                    &Pw[ln * 72 + 8 * lg + 32 * s]);
                bf16x8 vf;
                #pragma unroll
                for (int j = 0; j < 8; ++j) {
                    union { u16 u; __bf16 y; } cv;
                    cv.u = Vs[(8 * lg + 32 * s + j) * 76 + d0 * 16 + ln];
                    vf[j] = cv.y;
                }
                oacc[d0] = __builtin_amdgcn_mfma_f32_16x16x32_bf16(pf, vf, oacc[d0], 0, 0, 0);
            }
        }
    }

    // analytic null-key term + output (all processed q-rows are eligible)
    #pragma unroll
    for (int r = 0; r < 4; ++r) {
        float mf = mold[r];
        float M = (C < NSEQ) ? fmaxf(mf, 0.0f) : mf;
        float ec = __expf(mf - M);
        float lden = lsum[r] * ec +
                     ((C < NSEQ) ? (float)(NSEQ - C) * __expf(-M) : 0.0f);
        float rs = ec / lden;
        const int otok = pb[q0 + 4 * lg + r];
        u16* obp = o + (bbase + otok) * DMODEL + hh * 64;
        #pragma unroll
        for (int d0 = 0; d0 < 4; ++d0)
            obp[d0 * 16 + ln] = f2bf(oacc[d0][r] * rs);
    }
}

// ---------------------------------------------------------------------------
extern "C" void kernel_launch(void* const* d_in, const int* in_sizes, int n_in,
                              void* d_out, int out_size, void* d_ws, size_t ws_size,
                              hipStream_t stream)
{
    (void)in_sizes; (void)n_in; (void)out_size; (void)ws_size;
    const void* x    = d_in[0];
    const void* r_w  = d_in[1];
    const void* r_b  = d_in[2];
    const void* g1   = d_in[3];
    const void* b1   = d_in[4];
    const void* g2   = d_in[5];
    const void* b2   = d_in[6];
    const void* wqkv = d_in[7];
    const void* wo   = d_in[8];
    const void* bo   = d_in[9];
    const void* w1   = d_in[10];
    const void* b1f  = d_in[11];
    const void* w2   = d_in[12];
    const void* b2f  = d_in[13];
    const void* alp  = d_in[14];

    // Workspace overlay (~63.3 MB):
    //   [0,8M)    h / hm (bf16)
    //   [8M,32M)  qkv (bf16); later z (fp32) @ [8M,24M)
    //   [24M,56M) hid (bf16)  (after qkv dead)
    //   [32M,40M) ob (bf16)   (between attn and gemm1; inside hid's future range)
    //   [56M,62M) bf16 transposed weights
    //   [63M,..)  meta: flag, dtok, rpw, probs, sortedIdx, perm
    const size_t MB = 1024 * 1024;
    char* ws = (char*)d_ws;
    u16*   h      = (u16*)  (ws);
    u16*   hm     = (u16*)  (ws);
    u16*   qkv    = (u16*)  (ws + 8 * MB);
    float* z      = (float*)(ws + 8 * MB);
    u16*   hid    = (u16*)  (ws + 24 * MB);
    u16*   ob     = (u16*)  (ws + 32 * MB);
    u16*   wqkvT  = (u16*)  (ws + 56 * MB);                 // [1536][512]
    u16*   woT    = (u16*)  (ws + 56 * MB + 1572864);       // [512][512]
    u16*   w1T    = (u16*)  (ws + 56 * MB + 2097152);       // [2048][512]
    u16*   w2T    = (u16*)  (ws + 56 * MB + 4194304);       // [512][2048]
    int*   flag   = (int*)  (ws + 63 * MB);
    int*   dtok   = (int*)  (ws + 63 * MB + 1024);
    float* rpw    = (float*)(ws + 63 * MB + 1024 + 32768);
    float* probs  = (float*)(ws + 63 * MB + 1024 + 65536);          // [TOK][4]
    u16*   sorted = (u16*)  (ws + 63 * MB + 1024 + 65536 + 131072); // [B][3][2048]
    int*   perm   = (int*)  (ws + 63 * MB + 1024 + 65536 + 131072 + 49152); // [B][2048]

    detect_kernel<<<1, 256, 0, stream>>>((const u16*)x, flag);
    wconv_kernel<<<dim3(16, 48), 256, 0, stream>>>(wqkv, flag, wqkvT, 512, 1536);
    wconv_kernel<<<dim3(16, 16), 256, 0, stream>>>(wo,   flag, woT,   512, 512);
    wconv_kernel<<<dim3(16, 64), 256, 0, stream>>>(w1,   flag, w1T,   512, 2048);
    wconv_kernel<<<dim3(64, 16), 256, 0, stream>>>(w2,   flag, w2T,   2048, 512);
    rprob_kernel<<<TOK / 4, 256, 0, stream>>>(x, r_w, r_b, flag, probs);
    rsort_kernel<<<BATCH * 3, 1024, 0, stream>>>(probs, sorted);
    rassign_kernel<<<BATCH, 1024, 0, stream>>>(probs, sorted, flag, dtok, rpw, perm, d_out);
    ln_kernel<0><<<TOK, 256, 0, stream>>>(x, g1, b1, flag, dtok, h);
    mgemm_kernel<0><<<dim3(TOK / 128, 1536 / 64), 256, 0, stream>>>(
        h, wqkvT, nullptr, flag, dtok, nullptr, nullptr, nullptr, nullptr,
        qkv, nullptr, 1536, 512);
    hipMemsetAsync(ob, 0, (size_t)TOK * DMODEL * 2, stream);
    attn_kernel<<<BATCH * 80, 256, 0, stream>>>(qkv, perm, ob);
    mgemm_kernel<1><<<dim3(TOK / 128, 512 / 64), 256, 0, stream>>>(
        ob, woT, bo, flag, dtok, nullptr, x, nullptr, nullptr,
        nullptr, z, 512, 512);
    ln_kernel<1><<<TOK, 256, 0, stream>>>(z, g2, b2, flag, dtok, hm);
    mgemm_kernel<2><<<dim3(TOK / 128, 2048 / 64), 256, 0, stream>>>(
        hm, w1T, b1f, flag, dtok, nullptr, nullptr, nullptr, nullptr,
        hid, nullptr, 2048, 512);
    mgemm_kernel<3><<<dim3(TOK / 128, 512 / 64), 256, 0, stream>>>(
        hid, w2T, b2f, flag, dtok, rpw, nullptr, z, alp,
        d_out, nullptr, 512, 2048);
}